// Round 9
// baseline (470.577 us; speedup 1.0000x reference)
//
#include <hip/hip_runtime.h>
#include <hip/hip_bf16.h>
#include <cstddef>

#define NN 50000
#define EE 1600000
#define GG 512
#define NB 196        // ceil(NN/256) buckets of 256 nodes
#define BSTRIDE 16384 // fixed pairs-region capacity per bucket (max span ~8600)
#define BCAP 10240    // LDS staging per bucket
#define XBLKS 6250    // NN*32/256 x-convert blocks
#define SCBLKS 782    // ceil(EE/2048) bscatter blocks

typedef unsigned int u32;
typedef unsigned short u16;
typedef __attribute__((ext_vector_type(8))) short frag_ab;   // 8 bf16 = 4 VGPRs
typedef __attribute__((ext_vector_type(4))) float frag_cd;   // 4 fp32 acc

__device__ __forceinline__ void gl_lds16(const void* g, void* l) {
    __builtin_amdgcn_global_load_lds(
        (const __attribute__((address_space(1))) u32*)g,
        (__attribute__((address_space(3))) u32*)l, 16, 0, 0);
}
__device__ __forceinline__ float b2f_lo(u32 v) { return __uint_as_float(v << 16); }
__device__ __forceinline__ float b2f_hi(u32 v) { return __uint_as_float(v & 0xffff0000u); }
__device__ __forceinline__ float b2f(u32 v, int odd) { return odd ? b2f_hi(v) : b2f_lo(v); }
__device__ __forceinline__ u16 f2b(float x) {
    __hip_bfloat16 h = __float2bfloat16(x);
    return *(u16*)&h;
}
__device__ __forceinline__ u32 pack2(float lo, float hi) {
    return ((u32)f2b(hi) << 16) | f2b(lo);
}
__device__ __forceinline__ void acc2(float2& a, u32 v) {
    a.x += b2f_lo(v);
    a.y += b2f_hi(v);
}

// ---------------- fused: edge bucket-scatter + x->bf16 (row+slice) + weight prep ----------------

__global__ __launch_bounds__(256) void bscatter_prep_kernel(
    const int* __restrict__ ei, int* __restrict__ bcnt, u32* __restrict__ pairs,
    const float* __restrict__ x, u16* __restrict__ ax, u32* __restrict__ G1,
    const float* __restrict__ Wr1, const float* __restrict__ Wo1,
    const float* __restrict__ Wr2, const float* __restrict__ Wo2,
    const float* __restrict__ Wr3, const float* __restrict__ Wo3,
    const float* __restrict__ br3,
    u16* __restrict__ BT1, u16* __restrict__ BT2, u16* __restrict__ BT3,
    float* __restrict__ bias3) {
    __shared__ int lcnt[NB];
    __shared__ int lbase[NB];
    __shared__ unsigned short lpos[2048];
    int bid = blockIdx.x, t = threadIdx.x;
    if (bid < SCBLKS) {
        int e0 = bid * 2048;
        u32 pk[8];   // packed (src<<8)|(dst&255) stashed across phases
        int bk[8];
        for (int i = t; i < NB; i += 256) lcnt[i] = 0;
        __syncthreads();
#pragma unroll
        for (int i = 0; i < 8; ++i) {
            int e = e0 + i * 256 + t;
            if (e < EE) {
                int dst = ei[EE + e], src = ei[e];
                int b = dst >> 8;
                bk[i] = b;
                pk[i] = ((u32)src << 8) | (u32)(dst & 255);
                lpos[i * 256 + t] = (unsigned short)atomicAdd(&lcnt[b], 1);
            } else bk[i] = -1;
        }
        __syncthreads();
        for (int i = t; i < NB; i += 256) lbase[i] = atomicAdd(&bcnt[i], lcnt[i]);
        __syncthreads();
#pragma unroll
        for (int i = 0; i < 8; ++i) {
            if (bk[i] >= 0) {
                int pos = lbase[bk[i]] + (int)lpos[i * 256 + t];
                pairs[(size_t)bk[i] * BSTRIDE + pos] = pk[i];
            }
        }
    } else if (bid < SCBLKS + XBLKS) {
        int idx = (bid - SCBLKS) * 256 + t;
        int row = idx >> 5, q = idx & 31;     // q: 4-float group (u32 words 2q, 2q+1)
        float4 v = *(const float4*)(x + (size_t)row * 128 + q * 4);
        u32 w0 = pack2(v.x, v.y), w1 = pack2(v.z, v.w);
        // row-major (GEMM A cols 128..255)
        *(u32*)(ax + (size_t)row * 256 + 128 + q * 4) = w0;
        *(u32*)(ax + (size_t)row * 256 + 128 + q * 4 + 2) = w1;
        // slice-major gather copy: slice = q>>3, word-in-slice = (2q)&15
        uint2 r; r.x = w0; r.y = w1;
        *(uint2*)(G1 + ((size_t)(q >> 3) * NN + row) * 16 + ((2 * q) & 15)) = r;
    } else {
        int m = bid - SCBLKS - XBLKS;   // 0..255 output col
        int k = t;                       // reduction idx
        BT2[m * 256 + k] = f2b(k < 128 ? Wr2[k * 256 + m] : Wo2[(k - 128) * 256 + m]);
        BT3[m * 256 + k] = f2b(m < 128 ? Wr3[k * 128 + m] : Wo3[k * 128 + (m - 128)]);
        if (m < 128)
            BT1[m * 256 + k] = f2b(k < 128 ? Wr1[k * 128 + m] : Wo1[(k - 128) * 128 + m]);
        if (k == 0) bias3[m] = (m < 128) ? 0.f : br3[m - 128];
    }
}

// ---------------- CSR pass 2 (512 threads/block; srcl in u16) ----------------

__global__ __launch_bounds__(512) void bfill_kernel(const u32* __restrict__ pairs,
                                                    const int* __restrict__ bcnt,
                                                    int* __restrict__ ofs,
                                                    u16* __restrict__ srcl) {
    __shared__ int sc[256];
    __shared__ int cnts[256];
    __shared__ int lcnt[256];
    __shared__ int lcur[256];
    __shared__ int lbuf[BCAP];
    int b = blockIdx.x, t = threadIdx.x;
    if (t < 256) {
        int c = (t < NB) ? bcnt[t] : 0;
        cnts[t] = c;
        sc[t] = c;
        lcnt[t] = 0;
    }
    __syncthreads();
    for (int off = 1; off < 256; off <<= 1) {
        int v = (t >= off && t < 256) ? sc[t - off] : 0;
        __syncthreads();
        if (t < 256) sc[t] += v;
        __syncthreads();
    }
    int base = sc[b] - cnts[b];
    int span = cnts[b];
    const u32* pp = pairs + (size_t)b * BSTRIDE;
    for (int j = t; j < span; j += 512) atomicAdd(&lcnt[pp[j] & 255u], 1);
    __syncthreads();
    int nc = 0;
    if (t < 256) {
        nc = lcnt[t];
        sc[t] = nc;
    }
    __syncthreads();
    for (int off = 1; off < 256; off <<= 1) {
        int v = (t >= off && t < 256) ? sc[t - off] : 0;
        __syncthreads();
        if (t < 256) sc[t] += v;
        __syncthreads();
    }
    if (t < 256) {
        int excl = sc[t] - nc;
        int node = b * 256 + t;
        if (node < NN) ofs[node] = base + excl;
        lcur[t] = excl;
    }
    if (b == 0 && t == 256) ofs[NN] = EE;
    __syncthreads();
    for (int j = t; j < span; j += 512) {
        u32 p = pp[j];
        int pos = atomicAdd(&lcur[p & 255u], 1);
        int src = (int)(p >> 8);
        if (pos < BCAP) lbuf[pos] = src;
        else srcl[base + pos] = (u16)src;
    }
    __syncthreads();
    int lim = span < BCAP ? span : BCAP;
    for (int j = t; j < lim; j += 512) srcl[base + j] = (u16)lbuf[j];
}

// ---------------- slice-major pull ----------------
// G: [4][NN][16] u32 slice-major gather source. Block: slice = blockIdx&3 (XCD-
// pinned via %8 round-robin heuristic), 4 waves = 4 nodes. Wave: q=lane>>3 edge
// slot (8 edges/iter), l=lane&7 -> uint2 (4 bf16). Cross-q shfl reduce.

__global__ __launch_bounds__(256) void pull_slice_kernel(const u32* __restrict__ G,
                                                         const int* __restrict__ ofs,
                                                         const u16* __restrict__ srcl,
                                                         u32* __restrict__ outu,
                                                         int rowstride) {
    int s = blockIdx.x & 3;
    int node = (blockIdx.x >> 2) * 4 + (threadIdx.x >> 6);
    int lane = threadIdx.x & 63;
    int q = lane >> 3, l = lane & 7;
    const u32* Gs = G + (size_t)s * NN * 16;
    int lo = ofs[node], hi = ofs[node + 1];
    float2 a0 = {0.f, 0.f}, a1 = {0.f, 0.f};
    int j = lo;
    for (; j + 15 < hi; j += 16) {
        int s0 = srcl[j + q], s1 = srcl[j + 8 + q];
        uint2 v0 = *(const uint2*)(Gs + (size_t)s0 * 16 + l * 2);
        uint2 v1 = *(const uint2*)(Gs + (size_t)s1 * 16 + l * 2);
        acc2(a0, v0.x); acc2(a1, v0.y);
        acc2(a0, v1.x); acc2(a1, v1.y);
    }
    for (; j < hi; j += 8) {
        if (j + q < hi) {
            int s0 = srcl[j + q];
            uint2 v = *(const uint2*)(Gs + (size_t)s0 * 16 + l * 2);
            acc2(a0, v.x); acc2(a1, v.y);
        }
    }
    float acc[4] = {a0.x, a0.y, a1.x, a1.y};
#pragma unroll
    for (int i = 0; i < 4; ++i) {
        acc[i] += __shfl_xor(acc[i], 8, 64);
        acc[i] += __shfl_xor(acc[i], 16, 64);
        acc[i] += __shfl_xor(acc[i], 32, 64);
    }
    if (q == 0) {
        uint2 r;
        r.x = pack2(acc[0], acc[1]);
        r.y = pack2(acc[2], acc[3]);
        *(uint2*)(outu + (size_t)node * rowstride + s * 16 + l * 2) = r;
    }
}

// pull3: gather G3 (t3, slice-major) + add o3 (row-major [NN][64]u32) -> h3 [NN][64]u32.
__global__ __launch_bounds__(256) void pull3_slice_kernel(const u32* __restrict__ G,
                                                          const int* __restrict__ ofs,
                                                          const u16* __restrict__ srcl,
                                                          const u32* __restrict__ o3u,
                                                          u32* __restrict__ h3u) {
    int s = blockIdx.x & 3;
    int node = (blockIdx.x >> 2) * 4 + (threadIdx.x >> 6);
    int lane = threadIdx.x & 63;
    int q = lane >> 3, l = lane & 7;
    const u32* Gs = G + (size_t)s * NN * 16;
    int lo = ofs[node], hi = ofs[node + 1];
    float2 a0 = {0.f, 0.f}, a1 = {0.f, 0.f};
    int j = lo;
    for (; j + 15 < hi; j += 16) {
        int s0 = srcl[j + q], s1 = srcl[j + 8 + q];
        uint2 v0 = *(const uint2*)(Gs + (size_t)s0 * 16 + l * 2);
        uint2 v1 = *(const uint2*)(Gs + (size_t)s1 * 16 + l * 2);
        acc2(a0, v0.x); acc2(a1, v0.y);
        acc2(a0, v1.x); acc2(a1, v1.y);
    }
    for (; j < hi; j += 8) {
        if (j + q < hi) {
            int s0 = srcl[j + q];
            uint2 v = *(const uint2*)(Gs + (size_t)s0 * 16 + l * 2);
            acc2(a0, v.x); acc2(a1, v.y);
        }
    }
    float acc[4] = {a0.x, a0.y, a1.x, a1.y};
#pragma unroll
    for (int i = 0; i < 4; ++i) {
        acc[i] += __shfl_xor(acc[i], 8, 64);
        acc[i] += __shfl_xor(acc[i], 16, 64);
        acc[i] += __shfl_xor(acc[i], 32, 64);
    }
    if (q == 0) {
        uint2 o = *(const uint2*)(o3u + (size_t)node * 64 + s * 16 + l * 2);
        acc[0] += b2f_lo(o.x); acc[1] += b2f_hi(o.x);
        acc[2] += b2f_lo(o.y); acc[3] += b2f_hi(o.y);
        uint2 r;
        r.x = pack2(acc[0], acc[1]);
        r.y = pack2(acc[2], acc[3]);
        *(uint2*)(h3u + (size_t)node * 64 + s * 16 + l * 2) = r;
    }
}

// ---------------- bf16 MFMA GEMM: K=256, flexible epilogue ----------------
// col >= rowlo -> Crow[(row*ldc)+coloff+col]; col < slchi -> slice-major Cslc.

__global__ __launch_bounds__(256, 2) void gemm_bf_kernel(
    const u16* __restrict__ A, const u16* __restrict__ BT,
    const float* __restrict__ bias, u16* __restrict__ Crow,
    int ldc, int coloff, int rowlo, u16* __restrict__ Cslc, int slchi, int relu) {
    __shared__ alignas(16) u16 As[128 * 32];
    __shared__ alignas(16) u16 Bs[128 * 32];
    const int t = threadIdx.x;
    const int lane = t & 63, wid = t >> 6;
    const int quad = lane >> 4, l16 = lane & 15;
    const int wm = wid >> 1, wn = wid & 1;
    const int row0 = blockIdx.y * 128, c0 = blockIdx.x * 128;

    frag_cd acc[4][4];
#pragma unroll
    for (int i = 0; i < 4; ++i)
#pragma unroll
        for (int j = 0; j < 4; ++j) acc[i][j] = (frag_cd)0.f;

    const int ca = t, cb = t + 256;
    const int ra = ca >> 2, oa = (ca & 3) * 8;
    const int rb = cb >> 2, ob = (cb & 3) * 8;
    const int garow = min(row0 + ra, NN - 1);
    const int gbrow = min(row0 + rb, NN - 1);
    const size_t gA1 = (size_t)garow * 256 + oa;
    const size_t gA2 = (size_t)gbrow * 256 + ob;
    const size_t gB1 = (size_t)(c0 + ra) * 256 + oa;
    const size_t gB2 = (size_t)(c0 + rb) * 256 + ob;

    for (int kk = 0; kk < 256; kk += 32) {
        __syncthreads();
        gl_lds16(A + gA1 + kk, &As[ca * 8]);
        gl_lds16(A + gA2 + kk, &As[cb * 8]);
        gl_lds16(BT + gB1 + kk, &Bs[ca * 8]);
        gl_lds16(BT + gB2 + kk, &Bs[cb * 8]);
        __syncthreads();

        frag_ab a[4], b[4];
#pragma unroll
        for (int mt = 0; mt < 4; ++mt)
            a[mt] = *(const frag_ab*)&As[(wm * 64 + mt * 16 + l16) * 32 + quad * 8];
#pragma unroll
        for (int nt = 0; nt < 4; ++nt)
            b[nt] = *(const frag_ab*)&Bs[(wn * 64 + nt * 16 + l16) * 32 + quad * 8];
#pragma unroll
        for (int mt = 0; mt < 4; ++mt)
#pragma unroll
            for (int nt = 0; nt < 4; ++nt)
                acc[mt][nt] = __builtin_amdgcn_mfma_f32_16x16x32_bf16(
                    a[mt], b[nt], acc[mt][nt], 0, 0, 0);
    }

#pragma unroll
    for (int nt = 0; nt < 4; ++nt) {
        int col = c0 + wn * 64 + nt * 16 + l16;
        float bv = bias[col];
        int w = col >> 1, s = w >> 4, wis = w & 15, odd = col & 1;
#pragma unroll
        for (int mt = 0; mt < 4; ++mt) {
#pragma unroll
            for (int r = 0; r < 4; ++r) {
                int row = row0 + wm * 64 + mt * 16 + quad * 4 + r;
                if (row < NN) {
                    float v = acc[mt][nt][r] + bv;
                    if (relu) v = fmaxf(v, 0.f);
                    u16 bb = f2b(v);
                    if (col >= rowlo)
                        Crow[(size_t)row * ldc + coloff + col] = bb;
                    if (col < slchi)
                        Cslc[(((size_t)s * NN + row) * 16 + wis) * 2 + odd] = bb;
                }
            }
        }
    }
}

// ---------------- fused mean-pool + head (4 waves, unrolled scan) ----------------

__device__ inline int lower_bound_i(const int* a, int n, int v) {
    int lo = 0, hi = n;
    while (lo < hi) {
        int m = (lo + hi) >> 1;
        if (a[m] < v) lo = m + 1; else hi = m;
    }
    return lo;
}

__global__ __launch_bounds__(256) void pool_head_kernel(const u32* __restrict__ h3u,
                                                        const int* __restrict__ batch,
                                                        const float* __restrict__ W1,
                                                        const float* __restrict__ b1,
                                                        const float* __restrict__ W2,
                                                        const float* __restrict__ b2,
                                                        float* __restrict__ out) {
    __shared__ float ps[256];
    __shared__ float p[128];
    __shared__ float hid[40];
    int g = blockIdx.x, t = threadIdx.x;
    int c = t & 127, half = t >> 7;        // 2 row-groups x 128 channels
    int w = c >> 1, odd = c & 1;
    int lo = lower_bound_i(batch, NN, g);
    int hi = lower_bound_i(batch, NN, g + 1);
    float s = 0.f;
    int i = lo + half;
    for (; i + 6 < hi; i += 8) {           // 4 independent loads in flight
        u32 v0 = h3u[(size_t)i * 64 + w];
        u32 v1 = h3u[(size_t)(i + 2) * 64 + w];
        u32 v2 = h3u[(size_t)(i + 4) * 64 + w];
        u32 v3 = h3u[(size_t)(i + 6) * 64 + w];
        s += (b2f(v0, odd) + b2f(v1, odd)) + (b2f(v2, odd) + b2f(v3, odd));
    }
    for (; i < hi; i += 2) s += b2f(h3u[(size_t)i * 64 + w], odd);
    ps[t] = s;
    __syncthreads();
    if (half == 0) p[c] = (ps[c] + ps[c + 128]) / fmaxf((float)(hi - lo), 1.f);
    __syncthreads();
    if (t < 40) {
        float v = b1[t];
        for (int k = 0; k < 128; ++k) v += p[k] * W1[k * 40 + t];
        hid[t] = v;
    }
    __syncthreads();
    if (t < 10) {
        float v = b2[t];
        for (int j = 0; j < 40; ++j) v += hid[j] * W2[j * 10 + t];
        out[g * 10 + t] = v;
    }
}

// ---------------- launch ----------------

extern "C" void kernel_launch(void* const* d_in, const int* in_sizes, int n_in,
                              void* d_out, int out_size, void* d_ws, size_t ws_size,
                              hipStream_t stream) {
    const float* x   = (const float*)d_in[0];
    const int* ei    = (const int*)d_in[1];
    const int* batch = (const int*)d_in[2];
    const float* Wr1 = (const float*)d_in[3];
    const float* br1 = (const float*)d_in[4];
    const float* Wo1 = (const float*)d_in[5];
    const float* Wr2 = (const float*)d_in[6];
    const float* br2 = (const float*)d_in[7];
    const float* Wo2 = (const float*)d_in[8];
    const float* Wr3 = (const float*)d_in[9];
    const float* br3 = (const float*)d_in[10];
    const float* Wo3 = (const float*)d_in[11];
    const float* W1  = (const float*)d_in[12];
    const float* b1  = (const float*)d_in[13];
    const float* W2  = (const float*)d_in[14];
    const float* b2  = (const float*)d_in[15];
    float* out = (float*)d_out;

    char* ws = (char*)d_ws;
    size_t off = 0;
    auto alloc = [&](size_t bytes) {
        void* p = ws + off;
        off += (bytes + 255) & ~(size_t)255;
        return p;
    };
    int* ofs      = (int*)alloc((NN + 1) * sizeof(int));
    int* bcnt     = (int*)alloc(256 * sizeof(int));
    u16* srcl     = (u16*)alloc((size_t)EE * 2);
    u16* ax       = (u16*)alloc((size_t)NN * 256 * 2);   // A1: cols 0-127 agg, 128-255 x_bf
    u16* ah1      = (u16*)alloc((size_t)NN * 256 * 2);   // A2: cols 0-127 agg, 128-255 h1
    u16* h2       = (u16*)alloc((size_t)NN * 256 * 2);
    u32* G1       = (u32*)alloc((size_t)4 * NN * 16 * 4);  // slice-major x_bf
    u32* G2       = (u32*)alloc((size_t)4 * NN * 16 * 4);  // slice-major h1
    u32* G3       = (u32*)alloc((size_t)4 * NN * 16 * 4);  // slice-major t3
    u16* o3       = (u16*)alloc((size_t)NN * 128 * 2);     // row-major o3
    u16* h3       = (u16*)alloc((size_t)NN * 128 * 2);     // row-major h3 (bf16)
    u16* BT1      = (u16*)alloc(128 * 256 * 2);
    u16* BT2      = (u16*)alloc(256 * 256 * 2);
    u16* BT3      = (u16*)alloc(256 * 256 * 2);
    float* bias3  = (float*)alloc(256 * sizeof(float));
    // pairs (12.85 MB) overlays h2 (25.6 MB): pairs lifetime ends at bfill,
    // h2 first written at gemm2.
    u32* pairs = (u32*)h2;

    hipMemsetAsync(bcnt, 0, 256 * sizeof(int), stream);

    // CSR pass 1 + x->bf16 (row + slice) + weight prep
    bscatter_prep_kernel<<<SCBLKS + XBLKS + 256, 256, 0, stream>>>(
        ei, bcnt, pairs, x, ax, G1, Wr1, Wo1, Wr2, Wo2, Wr3, Wo3, br3,
        BT1, BT2, BT3, bias3);
    // CSR pass 2
    bfill_kernel<<<NB, 512, 0, stream>>>(pairs, bcnt, ofs, srcl);

    // conv1: agg(x) -> ax cols 0-127; gemm1 -> h1 (row into ah1 cols 128+, slice into G2)
    pull_slice_kernel<<<NN, 256, 0, stream>>>(G1, ofs, srcl, (u32*)ax, 128);
    gemm_bf_kernel<<<dim3(1, 391), 256, 0, stream>>>(ax, BT1, br1,
                                                     ah1, 256, 128, 0, (u16*)G2, 128, 1);
    // conv2: agg(h1) -> ah1 cols 0-127; gemm2 -> h2 (row-major only)
    pull_slice_kernel<<<NN, 256, 0, stream>>>(G2, ofs, srcl, (u32*)ah1, 128);
    gemm_bf_kernel<<<dim3(2, 391), 256, 0, stream>>>(ah1, BT2, br2,
                                                     h2, 256, 0, 0, nullptr, 0, 1);
    // conv3: cols 0-127 (t3) -> G3 slice-major; cols 128-255 (o3+br3) -> o3 row-major
    gemm_bf_kernel<<<dim3(2, 391), 256, 0, stream>>>(h2, BT3, bias3,
                                                     o3, 128, -128, 128, (u16*)G3, 128, 0);
    // h3 = agg(t3) + o3  (bf16)
    pull3_slice_kernel<<<NN, 256, 0, stream>>>(G3, ofs, srcl, (const u32*)o3, (u32*)h3);

    // fused mean pool + head
    pool_head_kernel<<<GG, 256, 0, stream>>>((const u32*)h3, batch, W1, b1, W2, b2, out);
}

// Round 10
// 461.697 us; speedup vs baseline: 1.0192x; 1.0192x over previous
//
#include <hip/hip_runtime.h>
#include <hip/hip_bf16.h>
#include <cstddef>

#define NN 50000
#define EE 1600000
#define GG 512
#define NB 196        // ceil(NN/256) buckets of 256 nodes
#define BSTRIDE 16384 // fixed pairs-region capacity per bucket (max span ~8600)
#define BCAP 10240    // LDS staging per bucket
#define XBLKS 6250    // NN*32/256 x-convert blocks
#define SCBLKS 782    // ceil(EE/2048) bscatter blocks

typedef unsigned int u32;
typedef unsigned short u16;
typedef __attribute__((ext_vector_type(8))) short frag_ab;   // 8 bf16 = 4 VGPRs
typedef __attribute__((ext_vector_type(4))) float frag_cd;   // 4 fp32 acc

__device__ __forceinline__ void gl_lds16(const void* g, void* l) {
    __builtin_amdgcn_global_load_lds(
        (const __attribute__((address_space(1))) u32*)g,
        (__attribute__((address_space(3))) u32*)l, 16, 0, 0);
}
__device__ __forceinline__ float b2f_lo(u32 v) { return __uint_as_float(v << 16); }
__device__ __forceinline__ float b2f_hi(u32 v) { return __uint_as_float(v & 0xffff0000u); }
__device__ __forceinline__ float b2f(u32 v, int odd) { return odd ? b2f_hi(v) : b2f_lo(v); }
__device__ __forceinline__ u16 f2b(float x) {
    __hip_bfloat16 h = __float2bfloat16(x);
    return *(u16*)&h;
}
__device__ __forceinline__ u32 pack2(float lo, float hi) {
    return ((u32)f2b(hi) << 16) | f2b(lo);
}
__device__ __forceinline__ void acc2(float2& a, u32 v) {
    a.x += b2f_lo(v);
    a.y += b2f_hi(v);
}

// ---------------- fused: edge bucket-scatter + x->bf16 (row+slice) + weight prep ----------------

__global__ __launch_bounds__(256) void bscatter_prep_kernel(
    const int* __restrict__ ei, int* __restrict__ bcnt, u32* __restrict__ pairs,
    const float* __restrict__ x, u16* __restrict__ ax, u32* __restrict__ G1,
    const float* __restrict__ Wr1, const float* __restrict__ Wo1,
    const float* __restrict__ Wr2, const float* __restrict__ Wo2,
    const float* __restrict__ Wr3, const float* __restrict__ Wo3,
    const float* __restrict__ br3,
    u16* __restrict__ BT1, u16* __restrict__ BT2, u16* __restrict__ BT3,
    float* __restrict__ bias3) {
    __shared__ int lcnt[NB];
    __shared__ int lbase[NB];
    __shared__ unsigned short lpos[2048];
    int bid = blockIdx.x, t = threadIdx.x;
    if (bid < SCBLKS) {
        int e0 = bid * 2048;
        u32 pk[8];   // packed (src<<8)|(dst&255) stashed across phases
        int bk[8];
        for (int i = t; i < NB; i += 256) lcnt[i] = 0;
        __syncthreads();
#pragma unroll
        for (int i = 0; i < 8; ++i) {
            int e = e0 + i * 256 + t;
            if (e < EE) {
                int dst = ei[EE + e], src = ei[e];
                int b = dst >> 8;
                bk[i] = b;
                pk[i] = ((u32)src << 8) | (u32)(dst & 255);
                lpos[i * 256 + t] = (unsigned short)atomicAdd(&lcnt[b], 1);
            } else bk[i] = -1;
        }
        __syncthreads();
        for (int i = t; i < NB; i += 256) lbase[i] = atomicAdd(&bcnt[i], lcnt[i]);
        __syncthreads();
#pragma unroll
        for (int i = 0; i < 8; ++i) {
            if (bk[i] >= 0) {
                int pos = lbase[bk[i]] + (int)lpos[i * 256 + t];
                pairs[(size_t)bk[i] * BSTRIDE + pos] = pk[i];
            }
        }
    } else if (bid < SCBLKS + XBLKS) {
        int idx = (bid - SCBLKS) * 256 + t;
        int row = idx >> 5, q = idx & 31;     // q: 4-float group (u32 words 2q, 2q+1)
        float4 v = *(const float4*)(x + (size_t)row * 128 + q * 4);
        u32 w0 = pack2(v.x, v.y), w1 = pack2(v.z, v.w);
        // row-major (GEMM A cols 128..255)
        *(u32*)(ax + (size_t)row * 256 + 128 + q * 4) = w0;
        *(u32*)(ax + (size_t)row * 256 + 128 + q * 4 + 2) = w1;
        // slice-major gather copy: slice = q>>3, word-in-slice = (2q)&15
        uint2 r; r.x = w0; r.y = w1;
        *(uint2*)(G1 + ((size_t)(q >> 3) * NN + row) * 16 + ((2 * q) & 15)) = r;
    } else {
        int m = bid - SCBLKS - XBLKS;   // 0..255 output col
        int k = t;                       // reduction idx
        BT2[m * 256 + k] = f2b(k < 128 ? Wr2[k * 256 + m] : Wo2[(k - 128) * 256 + m]);
        BT3[m * 256 + k] = f2b(m < 128 ? Wr3[k * 128 + m] : Wo3[k * 128 + (m - 128)]);
        if (m < 128)
            BT1[m * 256 + k] = f2b(k < 128 ? Wr1[k * 128 + m] : Wo1[(k - 128) * 128 + m]);
        if (k == 0) bias3[m] = (m < 128) ? 0.f : br3[m - 128];
    }
}

// ---------------- CSR pass 2 (512 threads/block; srcl in u16) ----------------

__global__ __launch_bounds__(512) void bfill_kernel(const u32* __restrict__ pairs,
                                                    const int* __restrict__ bcnt,
                                                    int* __restrict__ ofs,
                                                    u16* __restrict__ srcl) {
    __shared__ int sc[256];
    __shared__ int cnts[256];
    __shared__ int lcnt[256];
    __shared__ int lcur[256];
    __shared__ int lbuf[BCAP];
    int b = blockIdx.x, t = threadIdx.x;
    if (t < 256) {
        int c = (t < NB) ? bcnt[t] : 0;
        cnts[t] = c;
        sc[t] = c;
        lcnt[t] = 0;
    }
    __syncthreads();
    for (int off = 1; off < 256; off <<= 1) {
        int v = (t >= off && t < 256) ? sc[t - off] : 0;
        __syncthreads();
        if (t < 256) sc[t] += v;
        __syncthreads();
    }
    int base = sc[b] - cnts[b];
    int span = cnts[b];
    const u32* pp = pairs + (size_t)b * BSTRIDE;
    for (int j = t; j < span; j += 512) atomicAdd(&lcnt[pp[j] & 255u], 1);
    __syncthreads();
    int nc = 0;
    if (t < 256) {
        nc = lcnt[t];
        sc[t] = nc;
    }
    __syncthreads();
    for (int off = 1; off < 256; off <<= 1) {
        int v = (t >= off && t < 256) ? sc[t - off] : 0;
        __syncthreads();
        if (t < 256) sc[t] += v;
        __syncthreads();
    }
    if (t < 256) {
        int excl = sc[t] - nc;
        int node = b * 256 + t;
        if (node < NN) ofs[node] = base + excl;
        lcur[t] = excl;
    }
    if (b == 0 && t == 256) ofs[NN] = EE;
    __syncthreads();
    for (int j = t; j < span; j += 512) {
        u32 p = pp[j];
        int pos = atomicAdd(&lcur[p & 255u], 1);
        int src = (int)(p >> 8);
        if (pos < BCAP) lbuf[pos] = src;
        else srcl[base + pos] = (u16)src;
    }
    __syncthreads();
    int lim = span < BCAP ? span : BCAP;
    for (int j = t; j < lim; j += 512) srcl[base + j] = (u16)lbuf[j];
}

// ---------------- slice-major pull, v2 (dwordx4, 16 edges/instr) ----------------
// G: [4][NN][16] u32. slice = blockIdx&3 (XCD-pinned via %8 round-robin), 4
// waves = 4 nodes. Wave: q=lane>>2 edge slot (16/instr), l=lane&3 -> uint4
// (64 B = full slice row across 4 lanes). 32 edges per 2-load iter.

__global__ __launch_bounds__(256) void pull_slice_kernel(const u32* __restrict__ G,
                                                         const int* __restrict__ ofs,
                                                         const u16* __restrict__ srcl,
                                                         u32* __restrict__ outu,
                                                         int rowstride) {
    int s = blockIdx.x & 3;
    int node = (blockIdx.x >> 2) * 4 + (threadIdx.x >> 6);
    int lane = threadIdx.x & 63;
    int q = lane >> 2, l = lane & 3;
    const u32* Gs = G + (size_t)s * NN * 16;
    int lo = ofs[node], hi = ofs[node + 1];
    float2 a0 = {0.f, 0.f}, a1 = {0.f, 0.f}, a2 = {0.f, 0.f}, a3 = {0.f, 0.f};
    int j = lo;
    for (; j + 31 < hi; j += 32) {
        int s0 = srcl[j + q], s1 = srcl[j + 16 + q];
        uint4 v0 = *(const uint4*)(Gs + (size_t)s0 * 16 + l * 4);
        uint4 v1 = *(const uint4*)(Gs + (size_t)s1 * 16 + l * 4);
        acc2(a0, v0.x); acc2(a1, v0.y); acc2(a2, v0.z); acc2(a3, v0.w);
        acc2(a0, v1.x); acc2(a1, v1.y); acc2(a2, v1.z); acc2(a3, v1.w);
    }
    for (; j < hi; j += 16) {
        if (j + q < hi) {
            int s0 = srcl[j + q];
            uint4 v = *(const uint4*)(Gs + (size_t)s0 * 16 + l * 4);
            acc2(a0, v.x); acc2(a1, v.y); acc2(a2, v.z); acc2(a3, v.w);
        }
    }
    float acc[8] = {a0.x, a0.y, a1.x, a1.y, a2.x, a2.y, a3.x, a3.y};
#pragma unroll
    for (int i = 0; i < 8; ++i) {
        acc[i] += __shfl_xor(acc[i], 4, 64);
        acc[i] += __shfl_xor(acc[i], 8, 64);
        acc[i] += __shfl_xor(acc[i], 16, 64);
        acc[i] += __shfl_xor(acc[i], 32, 64);
    }
    if (q == 0) {
        uint4 r;
        r.x = pack2(acc[0], acc[1]);
        r.y = pack2(acc[2], acc[3]);
        r.z = pack2(acc[4], acc[5]);
        r.w = pack2(acc[6], acc[7]);
        *(uint4*)(outu + (size_t)node * rowstride + s * 16 + l * 4) = r;
    }
}

// pull3: gather G3 (t3, slice-major) + add o3 (row-major [NN][64]u32) -> h3 [NN][64]u32.
__global__ __launch_bounds__(256) void pull3_slice_kernel(const u32* __restrict__ G,
                                                          const int* __restrict__ ofs,
                                                          const u16* __restrict__ srcl,
                                                          const u32* __restrict__ o3u,
                                                          u32* __restrict__ h3u) {
    int s = blockIdx.x & 3;
    int node = (blockIdx.x >> 2) * 4 + (threadIdx.x >> 6);
    int lane = threadIdx.x & 63;
    int q = lane >> 2, l = lane & 3;
    const u32* Gs = G + (size_t)s * NN * 16;
    int lo = ofs[node], hi = ofs[node + 1];
    float2 a0 = {0.f, 0.f}, a1 = {0.f, 0.f}, a2 = {0.f, 0.f}, a3 = {0.f, 0.f};
    int j = lo;
    for (; j + 31 < hi; j += 32) {
        int s0 = srcl[j + q], s1 = srcl[j + 16 + q];
        uint4 v0 = *(const uint4*)(Gs + (size_t)s0 * 16 + l * 4);
        uint4 v1 = *(const uint4*)(Gs + (size_t)s1 * 16 + l * 4);
        acc2(a0, v0.x); acc2(a1, v0.y); acc2(a2, v0.z); acc2(a3, v0.w);
        acc2(a0, v1.x); acc2(a1, v1.y); acc2(a2, v1.z); acc2(a3, v1.w);
    }
    for (; j < hi; j += 16) {
        if (j + q < hi) {
            int s0 = srcl[j + q];
            uint4 v = *(const uint4*)(Gs + (size_t)s0 * 16 + l * 4);
            acc2(a0, v.x); acc2(a1, v.y); acc2(a2, v.z); acc2(a3, v.w);
        }
    }
    float acc[8] = {a0.x, a0.y, a1.x, a1.y, a2.x, a2.y, a3.x, a3.y};
#pragma unroll
    for (int i = 0; i < 8; ++i) {
        acc[i] += __shfl_xor(acc[i], 4, 64);
        acc[i] += __shfl_xor(acc[i], 8, 64);
        acc[i] += __shfl_xor(acc[i], 16, 64);
        acc[i] += __shfl_xor(acc[i], 32, 64);
    }
    if (q == 0) {
        uint4 o = *(const uint4*)(o3u + (size_t)node * 64 + s * 16 + l * 4);
        acc[0] += b2f_lo(o.x); acc[1] += b2f_hi(o.x);
        acc[2] += b2f_lo(o.y); acc[3] += b2f_hi(o.y);
        acc[4] += b2f_lo(o.z); acc[5] += b2f_hi(o.z);
        acc[6] += b2f_lo(o.w); acc[7] += b2f_hi(o.w);
        uint4 r;
        r.x = pack2(acc[0], acc[1]);
        r.y = pack2(acc[2], acc[3]);
        r.z = pack2(acc[4], acc[5]);
        r.w = pack2(acc[6], acc[7]);
        *(uint4*)(h3u + (size_t)node * 64 + s * 16 + l * 4) = r;
    }
}

// ---------------- bf16 MFMA GEMM: K=256, flexible epilogue ----------------
// col >= rowlo -> Crow[(row*ldc)+coloff+col]; col < slchi -> slice-major Cslc.

__global__ __launch_bounds__(256, 2) void gemm_bf_kernel(
    const u16* __restrict__ A, const u16* __restrict__ BT,
    const float* __restrict__ bias, u16* __restrict__ Crow,
    int ldc, int coloff, int rowlo, u16* __restrict__ Cslc, int slchi, int relu) {
    __shared__ alignas(16) u16 As[128 * 32];
    __shared__ alignas(16) u16 Bs[128 * 32];
    const int t = threadIdx.x;
    const int lane = t & 63, wid = t >> 6;
    const int quad = lane >> 4, l16 = lane & 15;
    const int wm = wid >> 1, wn = wid & 1;
    const int row0 = blockIdx.y * 128, c0 = blockIdx.x * 128;

    frag_cd acc[4][4];
#pragma unroll
    for (int i = 0; i < 4; ++i)
#pragma unroll
        for (int j = 0; j < 4; ++j) acc[i][j] = (frag_cd)0.f;

    const int ca = t, cb = t + 256;
    const int ra = ca >> 2, oa = (ca & 3) * 8;
    const int rb = cb >> 2, ob = (cb & 3) * 8;
    const int garow = min(row0 + ra, NN - 1);
    const int gbrow = min(row0 + rb, NN - 1);
    const size_t gA1 = (size_t)garow * 256 + oa;
    const size_t gA2 = (size_t)gbrow * 256 + ob;
    const size_t gB1 = (size_t)(c0 + ra) * 256 + oa;
    const size_t gB2 = (size_t)(c0 + rb) * 256 + ob;

    for (int kk = 0; kk < 256; kk += 32) {
        __syncthreads();
        gl_lds16(A + gA1 + kk, &As[ca * 8]);
        gl_lds16(A + gA2 + kk, &As[cb * 8]);
        gl_lds16(BT + gB1 + kk, &Bs[ca * 8]);
        gl_lds16(BT + gB2 + kk, &Bs[cb * 8]);
        __syncthreads();

        frag_ab a[4], b[4];
#pragma unroll
        for (int mt = 0; mt < 4; ++mt)
            a[mt] = *(const frag_ab*)&As[(wm * 64 + mt * 16 + l16) * 32 + quad * 8];
#pragma unroll
        for (int nt = 0; nt < 4; ++nt)
            b[nt] = *(const frag_ab*)&Bs[(wn * 64 + nt * 16 + l16) * 32 + quad * 8];
#pragma unroll
        for (int mt = 0; mt < 4; ++mt)
#pragma unroll
            for (int nt = 0; nt < 4; ++nt)
                acc[mt][nt] = __builtin_amdgcn_mfma_f32_16x16x32_bf16(
                    a[mt], b[nt], acc[mt][nt], 0, 0, 0);
    }

#pragma unroll
    for (int nt = 0; nt < 4; ++nt) {
        int col = c0 + wn * 64 + nt * 16 + l16;
        float bv = bias[col];
        int w = col >> 1, s = w >> 4, wis = w & 15, odd = col & 1;
#pragma unroll
        for (int mt = 0; mt < 4; ++mt) {
#pragma unroll
            for (int r = 0; r < 4; ++r) {
                int row = row0 + wm * 64 + mt * 16 + quad * 4 + r;
                if (row < NN) {
                    float v = acc[mt][nt][r] + bv;
                    if (relu) v = fmaxf(v, 0.f);
                    u16 bb = f2b(v);
                    if (col >= rowlo)
                        Crow[(size_t)row * ldc + coloff + col] = bb;
                    if (col < slchi)
                        Cslc[(((size_t)s * NN + row) * 16 + wis) * 2 + odd] = bb;
                }
            }
        }
    }
}

// ---------------- fused mean-pool + head (4 waves, unrolled scan) ----------------

__device__ inline int lower_bound_i(const int* a, int n, int v) {
    int lo = 0, hi = n;
    while (lo < hi) {
        int m = (lo + hi) >> 1;
        if (a[m] < v) lo = m + 1; else hi = m;
    }
    return lo;
}

__global__ __launch_bounds__(256) void pool_head_kernel(const u32* __restrict__ h3u,
                                                        const int* __restrict__ batch,
                                                        const float* __restrict__ W1,
                                                        const float* __restrict__ b1,
                                                        const float* __restrict__ W2,
                                                        const float* __restrict__ b2,
                                                        float* __restrict__ out) {
    __shared__ float ps[256];
    __shared__ float p[128];
    __shared__ float hid[40];
    int g = blockIdx.x, t = threadIdx.x;
    int c = t & 127, half = t >> 7;        // 2 row-groups x 128 channels
    int w = c >> 1, odd = c & 1;
    int lo = lower_bound_i(batch, NN, g);
    int hi = lower_bound_i(batch, NN, g + 1);
    float s = 0.f;
    int i = lo + half;
    for (; i + 6 < hi; i += 8) {           // 4 independent loads in flight
        u32 v0 = h3u[(size_t)i * 64 + w];
        u32 v1 = h3u[(size_t)(i + 2) * 64 + w];
        u32 v2 = h3u[(size_t)(i + 4) * 64 + w];
        u32 v3 = h3u[(size_t)(i + 6) * 64 + w];
        s += (b2f(v0, odd) + b2f(v1, odd)) + (b2f(v2, odd) + b2f(v3, odd));
    }
    for (; i < hi; i += 2) s += b2f(h3u[(size_t)i * 64 + w], odd);
    ps[t] = s;
    __syncthreads();
    if (half == 0) p[c] = (ps[c] + ps[c + 128]) / fmaxf((float)(hi - lo), 1.f);
    __syncthreads();
    if (t < 40) {
        float v = b1[t];
        for (int k = 0; k < 128; ++k) v += p[k] * W1[k * 40 + t];
        hid[t] = v;
    }
    __syncthreads();
    if (t < 10) {
        float v = b2[t];
        for (int j = 0; j < 40; ++j) v += hid[j] * W2[j * 10 + t];
        out[g * 10 + t] = v;
    }
}

// ---------------- launch ----------------

extern "C" void kernel_launch(void* const* d_in, const int* in_sizes, int n_in,
                              void* d_out, int out_size, void* d_ws, size_t ws_size,
                              hipStream_t stream) {
    const float* x   = (const float*)d_in[0];
    const int* ei    = (const int*)d_in[1];
    const int* batch = (const int*)d_in[2];
    const float* Wr1 = (const float*)d_in[3];
    const float* br1 = (const float*)d_in[4];
    const float* Wo1 = (const float*)d_in[5];
    const float* Wr2 = (const float*)d_in[6];
    const float* br2 = (const float*)d_in[7];
    const float* Wo2 = (const float*)d_in[8];
    const float* Wr3 = (const float*)d_in[9];
    const float* br3 = (const float*)d_in[10];
    const float* Wo3 = (const float*)d_in[11];
    const float* W1  = (const float*)d_in[12];
    const float* b1  = (const float*)d_in[13];
    const float* W2  = (const float*)d_in[14];
    const float* b2  = (const float*)d_in[15];
    float* out = (float*)d_out;

    char* ws = (char*)d_ws;
    size_t off = 0;
    auto alloc = [&](size_t bytes) {
        void* p = ws + off;
        off += (bytes + 255) & ~(size_t)255;
        return p;
    };
    int* ofs      = (int*)alloc((NN + 1) * sizeof(int));
    int* bcnt     = (int*)alloc(256 * sizeof(int));
    u16* srcl     = (u16*)alloc((size_t)EE * 2);
    u16* ax       = (u16*)alloc((size_t)NN * 256 * 2);   // A1: cols 0-127 agg, 128-255 x_bf
    u16* ah1      = (u16*)alloc((size_t)NN * 256 * 2);   // A2: cols 0-127 agg, 128-255 h1
    u16* h2       = (u16*)alloc((size_t)NN * 256 * 2);
    u32* G1       = (u32*)alloc((size_t)4 * NN * 16 * 4);  // slice-major x_bf
    u32* G2       = (u32*)alloc((size_t)4 * NN * 16 * 4);  // slice-major h1
    u32* G3       = (u32*)alloc((size_t)4 * NN * 16 * 4);  // slice-major t3
    u16* o3       = (u16*)alloc((size_t)NN * 128 * 2);     // row-major o3
    u16* h3       = (u16*)alloc((size_t)NN * 128 * 2);     // row-major h3 (bf16)
    u16* BT1      = (u16*)alloc(128 * 256 * 2);
    u16* BT2      = (u16*)alloc(256 * 256 * 2);
    u16* BT3      = (u16*)alloc(256 * 256 * 2);
    float* bias3  = (float*)alloc(256 * sizeof(float));
    // pairs (12.85 MB) overlays h2 (25.6 MB): pairs lifetime ends at bfill,
    // h2 first written at gemm2.
    u32* pairs = (u32*)h2;

    hipMemsetAsync(bcnt, 0, 256 * sizeof(int), stream);

    // CSR pass 1 + x->bf16 (row + slice) + weight prep
    bscatter_prep_kernel<<<SCBLKS + XBLKS + 256, 256, 0, stream>>>(
        ei, bcnt, pairs, x, ax, G1, Wr1, Wo1, Wr2, Wo2, Wr3, Wo3, br3,
        BT1, BT2, BT3, bias3);
    // CSR pass 2
    bfill_kernel<<<NB, 512, 0, stream>>>(pairs, bcnt, ofs, srcl);

    // conv1: agg(x) -> ax cols 0-127; gemm1 -> h1 (row into ah1 cols 128+, slice into G2)
    pull_slice_kernel<<<NN, 256, 0, stream>>>(G1, ofs, srcl, (u32*)ax, 128);
    gemm_bf_kernel<<<dim3(1, 391), 256, 0, stream>>>(ax, BT1, br1,
                                                     ah1, 256, 128, 0, (u16*)G2, 128, 1);
    // conv2: agg(h1) -> ah1 cols 0-127; gemm2 -> h2 (row-major only)
    pull_slice_kernel<<<NN, 256, 0, stream>>>(G2, ofs, srcl, (u32*)ah1, 128);
    gemm_bf_kernel<<<dim3(2, 391), 256, 0, stream>>>(ah1, BT2, br2,
                                                     h2, 256, 0, 0, nullptr, 0, 1);
    // conv3: cols 0-127 (t3) -> G3 slice-major; cols 128-255 (o3+br3) -> o3 row-major
    gemm_bf_kernel<<<dim3(2, 391), 256, 0, stream>>>(h2, BT3, bias3,
                                                     o3, 128, -128, 128, (u16*)G3, 128, 0);
    // h3 = agg(t3) + o3  (bf16)
    pull3_slice_kernel<<<NN, 256, 0, stream>>>(G3, ofs, srcl, (const u32*)o3, (u32*)h3);

    // fused mean pool + head
    pool_head_kernel<<<GG, 256, 0, stream>>>((const u32*)h3, batch, W1, b1, W2, b2, out);
}

// Round 11
// 397.839 us; speedup vs baseline: 1.1828x; 1.1605x over previous
//
#include <hip/hip_runtime.h>
#include <hip/hip_bf16.h>
#include <cstddef>

#define NN 50000
#define EE 1600000
#define GG 512
#define NB 196        // ceil(NN/256) buckets of 256 nodes
#define BSTRIDE 16384 // fixed pairs-region capacity per bucket (max span ~8600)
#define BCAP 10240    // LDS staging per bucket
#define XBLKS 6250    // NN*32/256 x-convert blocks
#define SCBLKS 782    // ceil(EE/2048) bscatter blocks

typedef unsigned int u32;
typedef unsigned short u16;
typedef __attribute__((ext_vector_type(8))) short frag_ab;   // 8 bf16 = 4 VGPRs
typedef __attribute__((ext_vector_type(4))) float frag_cd;   // 4 fp32 acc

__device__ __forceinline__ void gl_lds16(const void* g, void* l) {
    __builtin_amdgcn_global_load_lds(
        (const __attribute__((address_space(1))) u32*)g,
        (__attribute__((address_space(3))) u32*)l, 16, 0, 0);
}
__device__ __forceinline__ float b2f_lo(u32 v) { return __uint_as_float(v << 16); }
__device__ __forceinline__ float b2f_hi(u32 v) { return __uint_as_float(v & 0xffff0000u); }
__device__ __forceinline__ float b2f(u32 v, int odd) { return odd ? b2f_hi(v) : b2f_lo(v); }
__device__ __forceinline__ u16 f2b(float x) {
    __hip_bfloat16 h = __float2bfloat16(x);
    return *(u16*)&h;
}
__device__ __forceinline__ u32 pack2(float lo, float hi) {
    return ((u32)f2b(hi) << 16) | f2b(lo);
}
__device__ __forceinline__ void acc2(float2& a, u32 v) {
    a.x += b2f_lo(v);
    a.y += b2f_hi(v);
}

// ---------------- fused: edge bucket-scatter + x->bf16 (row+slice) + weight prep ----------------

__global__ __launch_bounds__(256) void bscatter_prep_kernel(
    const int* __restrict__ ei, int* __restrict__ bcnt, u32* __restrict__ pairs,
    const float* __restrict__ x, u16* __restrict__ ax, u32* __restrict__ G1,
    const float* __restrict__ Wr1, const float* __restrict__ Wo1,
    const float* __restrict__ Wr2, const float* __restrict__ Wo2,
    const float* __restrict__ Wr3, const float* __restrict__ Wo3,
    const float* __restrict__ br3,
    u16* __restrict__ BT1, u16* __restrict__ BT2, u16* __restrict__ BT3,
    float* __restrict__ bias3) {
    __shared__ int lcnt[NB];
    __shared__ int lbase[NB];
    __shared__ unsigned short lpos[2048];
    int bid = blockIdx.x, t = threadIdx.x;
    if (bid < SCBLKS) {
        int e0 = bid * 2048;
        u32 pk[8];   // packed (src<<8)|(dst&255) stashed across phases
        int bk[8];
        for (int i = t; i < NB; i += 256) lcnt[i] = 0;
        __syncthreads();
#pragma unroll
        for (int i = 0; i < 8; ++i) {
            int e = e0 + i * 256 + t;
            if (e < EE) {
                int dst = ei[EE + e], src = ei[e];
                int b = dst >> 8;
                bk[i] = b;
                pk[i] = ((u32)src << 8) | (u32)(dst & 255);
                lpos[i * 256 + t] = (unsigned short)atomicAdd(&lcnt[b], 1);
            } else bk[i] = -1;
        }
        __syncthreads();
        for (int i = t; i < NB; i += 256) lbase[i] = atomicAdd(&bcnt[i], lcnt[i]);
        __syncthreads();
#pragma unroll
        for (int i = 0; i < 8; ++i) {
            if (bk[i] >= 0) {
                int pos = lbase[bk[i]] + (int)lpos[i * 256 + t];
                pairs[(size_t)bk[i] * BSTRIDE + pos] = pk[i];
            }
        }
    } else if (bid < SCBLKS + XBLKS) {
        int idx = (bid - SCBLKS) * 256 + t;
        int row = idx >> 5, q = idx & 31;     // q: 4-float group (u32 words 2q, 2q+1)
        float4 v = *(const float4*)(x + (size_t)row * 128 + q * 4);
        u32 w0 = pack2(v.x, v.y), w1 = pack2(v.z, v.w);
        // row-major (GEMM A cols 128..255)
        *(u32*)(ax + (size_t)row * 256 + 128 + q * 4) = w0;
        *(u32*)(ax + (size_t)row * 256 + 128 + q * 4 + 2) = w1;
        // slice-major gather copy: slice = q>>3, word-in-slice = (2q)&15
        uint2 r; r.x = w0; r.y = w1;
        *(uint2*)(G1 + ((size_t)(q >> 3) * NN + row) * 16 + ((2 * q) & 15)) = r;
    } else {
        int m = bid - SCBLKS - XBLKS;   // 0..255 output col
        int k = t;                       // reduction idx
        BT2[m * 256 + k] = f2b(k < 128 ? Wr2[k * 256 + m] : Wo2[(k - 128) * 256 + m]);
        BT3[m * 256 + k] = f2b(m < 128 ? Wr3[k * 128 + m] : Wo3[k * 128 + (m - 128)]);
        if (m < 128)
            BT1[m * 256 + k] = f2b(k < 128 ? Wr1[k * 128 + m] : Wo1[(k - 128) * 128 + m]);
        if (k == 0) bias3[m] = (m < 128) ? 0.f : br3[m - 128];
    }
}

// ---------------- CSR pass 2 (512 threads/block; srcl in u16) ----------------

__global__ __launch_bounds__(512) void bfill_kernel(const u32* __restrict__ pairs,
                                                    const int* __restrict__ bcnt,
                                                    int* __restrict__ ofs,
                                                    u16* __restrict__ srcl) {
    __shared__ int sc[256];
    __shared__ int cnts[256];
    __shared__ int lcnt[256];
    __shared__ int lcur[256];
    __shared__ int lbuf[BCAP];
    int b = blockIdx.x, t = threadIdx.x;
    if (t < 256) {
        int c = (t < NB) ? bcnt[t] : 0;
        cnts[t] = c;
        sc[t] = c;
        lcnt[t] = 0;
    }
    __syncthreads();
    for (int off = 1; off < 256; off <<= 1) {
        int v = (t >= off && t < 256) ? sc[t - off] : 0;
        __syncthreads();
        if (t < 256) sc[t] += v;
        __syncthreads();
    }
    int base = sc[b] - cnts[b];
    int span = cnts[b];
    const u32* pp = pairs + (size_t)b * BSTRIDE;
    for (int j = t; j < span; j += 512) atomicAdd(&lcnt[pp[j] & 255u], 1);
    __syncthreads();
    int nc = 0;
    if (t < 256) {
        nc = lcnt[t];
        sc[t] = nc;
    }
    __syncthreads();
    for (int off = 1; off < 256; off <<= 1) {
        int v = (t >= off && t < 256) ? sc[t - off] : 0;
        __syncthreads();
        if (t < 256) sc[t] += v;
        __syncthreads();
    }
    if (t < 256) {
        int excl = sc[t] - nc;
        int node = b * 256 + t;
        if (node < NN) ofs[node] = base + excl;
        lcur[t] = excl;
    }
    if (b == 0 && t == 256) ofs[NN] = EE;
    __syncthreads();
    for (int j = t; j < span; j += 512) {
        u32 p = pp[j];
        int pos = atomicAdd(&lcur[p & 255u], 1);
        int src = (int)(p >> 8);
        if (pos < BCAP) lbuf[pos] = src;
        else srcl[base + pos] = (u16)src;
    }
    __syncthreads();
    int lim = span < BCAP ? span : BCAP;
    for (int j = t; j < lim; j += 512) srcl[base + j] = (u16)lbuf[j];
}

// ---------------- slice-major pull, v3: 4 nodes per wave ----------------
// G: [4][NN][16] u32. slice = blockIdx&3 (XCD-pinned via %8 round-robin).
// Wave: nd=lane>>4 (node), eq=(lane>>2)&3 (edge slot), wg=lane&3 (uint4 word
// group; 4 lanes cover the 64-B slice row). 8 edges/node per iter (unroll 2).
// Epilogue: 2 shfl rounds (xor 4, 8) within each 16-lane node group.

__global__ __launch_bounds__(256) void pull_slice_kernel(const u32* __restrict__ G,
                                                         const int* __restrict__ ofs,
                                                         const u16* __restrict__ srcl,
                                                         u32* __restrict__ outu,
                                                         int rowstride) {
    int s = blockIdx.x & 3;
    int lane = threadIdx.x & 63;
    int node = (blockIdx.x >> 2) * 16 + ((threadIdx.x >> 6) << 2) + (lane >> 4);
    int eq = (lane >> 2) & 3, wg = lane & 3;
    const u32* Gs = G + (size_t)s * NN * 16;
    int lo = ofs[node], hi = ofs[node + 1];
    float2 a0 = {0.f, 0.f}, a1 = {0.f, 0.f}, a2 = {0.f, 0.f}, a3 = {0.f, 0.f};
    int j = lo + eq;
    while (__any(j < hi)) {
        if (j < hi) {
            int s0 = srcl[j];
            uint4 v = *(const uint4*)(Gs + (size_t)s0 * 16 + wg * 4);
            acc2(a0, v.x); acc2(a1, v.y); acc2(a2, v.z); acc2(a3, v.w);
        }
        if (j + 4 < hi) {
            int s1 = srcl[j + 4];
            uint4 v = *(const uint4*)(Gs + (size_t)s1 * 16 + wg * 4);
            acc2(a0, v.x); acc2(a1, v.y); acc2(a2, v.z); acc2(a3, v.w);
        }
        j += 8;
    }
    float acc[8] = {a0.x, a0.y, a1.x, a1.y, a2.x, a2.y, a3.x, a3.y};
#pragma unroll
    for (int i = 0; i < 8; ++i) {
        acc[i] += __shfl_xor(acc[i], 4, 64);
        acc[i] += __shfl_xor(acc[i], 8, 64);
    }
    if (eq == 0) {
        uint4 r;
        r.x = pack2(acc[0], acc[1]);
        r.y = pack2(acc[2], acc[3]);
        r.z = pack2(acc[4], acc[5]);
        r.w = pack2(acc[6], acc[7]);
        *(uint4*)(outu + (size_t)node * rowstride + s * 16 + wg * 4) = r;
    }
}

// pull3: gather G3 (t3, slice-major) + add o3 (row-major [NN][64]u32) -> h3 [NN][64]u32.
__global__ __launch_bounds__(256) void pull3_slice_kernel(const u32* __restrict__ G,
                                                          const int* __restrict__ ofs,
                                                          const u16* __restrict__ srcl,
                                                          const u32* __restrict__ o3u,
                                                          u32* __restrict__ h3u) {
    int s = blockIdx.x & 3;
    int lane = threadIdx.x & 63;
    int node = (blockIdx.x >> 2) * 16 + ((threadIdx.x >> 6) << 2) + (lane >> 4);
    int eq = (lane >> 2) & 3, wg = lane & 3;
    const u32* Gs = G + (size_t)s * NN * 16;
    int lo = ofs[node], hi = ofs[node + 1];
    float2 a0 = {0.f, 0.f}, a1 = {0.f, 0.f}, a2 = {0.f, 0.f}, a3 = {0.f, 0.f};
    int j = lo + eq;
    while (__any(j < hi)) {
        if (j < hi) {
            int s0 = srcl[j];
            uint4 v = *(const uint4*)(Gs + (size_t)s0 * 16 + wg * 4);
            acc2(a0, v.x); acc2(a1, v.y); acc2(a2, v.z); acc2(a3, v.w);
        }
        if (j + 4 < hi) {
            int s1 = srcl[j + 4];
            uint4 v = *(const uint4*)(Gs + (size_t)s1 * 16 + wg * 4);
            acc2(a0, v.x); acc2(a1, v.y); acc2(a2, v.z); acc2(a3, v.w);
        }
        j += 8;
    }
    float acc[8] = {a0.x, a0.y, a1.x, a1.y, a2.x, a2.y, a3.x, a3.y};
#pragma unroll
    for (int i = 0; i < 8; ++i) {
        acc[i] += __shfl_xor(acc[i], 4, 64);
        acc[i] += __shfl_xor(acc[i], 8, 64);
    }
    if (eq == 0) {
        uint4 o = *(const uint4*)(o3u + (size_t)node * 64 + s * 16 + wg * 4);
        acc[0] += b2f_lo(o.x); acc[1] += b2f_hi(o.x);
        acc[2] += b2f_lo(o.y); acc[3] += b2f_hi(o.y);
        acc[4] += b2f_lo(o.z); acc[5] += b2f_hi(o.z);
        acc[6] += b2f_lo(o.w); acc[7] += b2f_hi(o.w);
        uint4 r;
        r.x = pack2(acc[0], acc[1]);
        r.y = pack2(acc[2], acc[3]);
        r.z = pack2(acc[4], acc[5]);
        r.w = pack2(acc[6], acc[7]);
        *(uint4*)(h3u + (size_t)node * 64 + s * 16 + wg * 4) = r;
    }
}

// ---------------- bf16 MFMA GEMM: K=256, flexible epilogue ----------------
// col >= rowlo -> Crow[(row*ldc)+coloff+col]; col < slchi -> slice-major Cslc.

__global__ __launch_bounds__(256, 2) void gemm_bf_kernel(
    const u16* __restrict__ A, const u16* __restrict__ BT,
    const float* __restrict__ bias, u16* __restrict__ Crow,
    int ldc, int coloff, int rowlo, u16* __restrict__ Cslc, int slchi, int relu) {
    __shared__ alignas(16) u16 As[128 * 32];
    __shared__ alignas(16) u16 Bs[128 * 32];
    const int t = threadIdx.x;
    const int lane = t & 63, wid = t >> 6;
    const int quad = lane >> 4, l16 = lane & 15;
    const int wm = wid >> 1, wn = wid & 1;
    const int row0 = blockIdx.y * 128, c0 = blockIdx.x * 128;

    frag_cd acc[4][4];
#pragma unroll
    for (int i = 0; i < 4; ++i)
#pragma unroll
        for (int j = 0; j < 4; ++j) acc[i][j] = (frag_cd)0.f;

    const int ca = t, cb = t + 256;
    const int ra = ca >> 2, oa = (ca & 3) * 8;
    const int rb = cb >> 2, ob = (cb & 3) * 8;
    const int garow = min(row0 + ra, NN - 1);
    const int gbrow = min(row0 + rb, NN - 1);
    const size_t gA1 = (size_t)garow * 256 + oa;
    const size_t gA2 = (size_t)gbrow * 256 + ob;
    const size_t gB1 = (size_t)(c0 + ra) * 256 + oa;
    const size_t gB2 = (size_t)(c0 + rb) * 256 + ob;

    for (int kk = 0; kk < 256; kk += 32) {
        __syncthreads();
        gl_lds16(A + gA1 + kk, &As[ca * 8]);
        gl_lds16(A + gA2 + kk, &As[cb * 8]);
        gl_lds16(BT + gB1 + kk, &Bs[ca * 8]);
        gl_lds16(BT + gB2 + kk, &Bs[cb * 8]);
        __syncthreads();

        frag_ab a[4], b[4];
#pragma unroll
        for (int mt = 0; mt < 4; ++mt)
            a[mt] = *(const frag_ab*)&As[(wm * 64 + mt * 16 + l16) * 32 + quad * 8];
#pragma unroll
        for (int nt = 0; nt < 4; ++nt)
            b[nt] = *(const frag_ab*)&Bs[(wn * 64 + nt * 16 + l16) * 32 + quad * 8];
#pragma unroll
        for (int mt = 0; mt < 4; ++mt)
#pragma unroll
            for (int nt = 0; nt < 4; ++nt)
                acc[mt][nt] = __builtin_amdgcn_mfma_f32_16x16x32_bf16(
                    a[mt], b[nt], acc[mt][nt], 0, 0, 0);
    }

#pragma unroll
    for (int nt = 0; nt < 4; ++nt) {
        int col = c0 + wn * 64 + nt * 16 + l16;
        float bv = bias[col];
        int w = col >> 1, s = w >> 4, wis = w & 15, odd = col & 1;
#pragma unroll
        for (int mt = 0; mt < 4; ++mt) {
#pragma unroll
            for (int r = 0; r < 4; ++r) {
                int row = row0 + wm * 64 + mt * 16 + quad * 4 + r;
                if (row < NN) {
                    float v = acc[mt][nt][r] + bv;
                    if (relu) v = fmaxf(v, 0.f);
                    u16 bb = f2b(v);
                    if (col >= rowlo)
                        Crow[(size_t)row * ldc + coloff + col] = bb;
                    if (col < slchi)
                        Cslc[(((size_t)s * NN + row) * 16 + wis) * 2 + odd] = bb;
                }
            }
        }
    }
}

// ---------------- fused mean-pool + head (4 waves, unrolled scan) ----------------

__device__ inline int lower_bound_i(const int* a, int n, int v) {
    int lo = 0, hi = n;
    while (lo < hi) {
        int m = (lo + hi) >> 1;
        if (a[m] < v) lo = m + 1; else hi = m;
    }
    return lo;
}

__global__ __launch_bounds__(256) void pool_head_kernel(const u32* __restrict__ h3u,
                                                        const int* __restrict__ batch,
                                                        const float* __restrict__ W1,
                                                        const float* __restrict__ b1,
                                                        const float* __restrict__ W2,
                                                        const float* __restrict__ b2,
                                                        float* __restrict__ out) {
    __shared__ float ps[256];
    __shared__ float p[128];
    __shared__ float hid[40];
    int g = blockIdx.x, t = threadIdx.x;
    int c = t & 127, half = t >> 7;        // 2 row-groups x 128 channels
    int w = c >> 1, odd = c & 1;
    int lo = lower_bound_i(batch, NN, g);
    int hi = lower_bound_i(batch, NN, g + 1);
    float s = 0.f;
    int i = lo + half;
    for (; i + 6 < hi; i += 8) {           // 4 independent loads in flight
        u32 v0 = h3u[(size_t)i * 64 + w];
        u32 v1 = h3u[(size_t)(i + 2) * 64 + w];
        u32 v2 = h3u[(size_t)(i + 4) * 64 + w];
        u32 v3 = h3u[(size_t)(i + 6) * 64 + w];
        s += (b2f(v0, odd) + b2f(v1, odd)) + (b2f(v2, odd) + b2f(v3, odd));
    }
    for (; i < hi; i += 2) s += b2f(h3u[(size_t)i * 64 + w], odd);
    ps[t] = s;
    __syncthreads();
    if (half == 0) p[c] = (ps[c] + ps[c + 128]) / fmaxf((float)(hi - lo), 1.f);
    __syncthreads();
    if (t < 40) {
        float v = b1[t];
        for (int k = 0; k < 128; ++k) v += p[k] * W1[k * 40 + t];
        hid[t] = v;
    }
    __syncthreads();
    if (t < 10) {
        float v = b2[t];
        for (int j = 0; j < 40; ++j) v += hid[j] * W2[j * 10 + t];
        out[g * 10 + t] = v;
    }
}

// ---------------- launch ----------------

extern "C" void kernel_launch(void* const* d_in, const int* in_sizes, int n_in,
                              void* d_out, int out_size, void* d_ws, size_t ws_size,
                              hipStream_t stream) {
    const float* x   = (const float*)d_in[0];
    const int* ei    = (const int*)d_in[1];
    const int* batch = (const int*)d_in[2];
    const float* Wr1 = (const float*)d_in[3];
    const float* br1 = (const float*)d_in[4];
    const float* Wo1 = (const float*)d_in[5];
    const float* Wr2 = (const float*)d_in[6];
    const float* br2 = (const float*)d_in[7];
    const float* Wo2 = (const float*)d_in[8];
    const float* Wr3 = (const float*)d_in[9];
    const float* br3 = (const float*)d_in[10];
    const float* Wo3 = (const float*)d_in[11];
    const float* W1  = (const float*)d_in[12];
    const float* b1  = (const float*)d_in[13];
    const float* W2  = (const float*)d_in[14];
    const float* b2  = (const float*)d_in[15];
    float* out = (float*)d_out;

    char* ws = (char*)d_ws;
    size_t off = 0;
    auto alloc = [&](size_t bytes) {
        void* p = ws + off;
        off += (bytes + 255) & ~(size_t)255;
        return p;
    };
    int* ofs      = (int*)alloc((NN + 1) * sizeof(int));
    int* bcnt     = (int*)alloc(256 * sizeof(int));
    u16* srcl     = (u16*)alloc((size_t)EE * 2);
    u16* ax       = (u16*)alloc((size_t)NN * 256 * 2);   // A1: cols 0-127 agg, 128-255 x_bf
    u16* ah1      = (u16*)alloc((size_t)NN * 256 * 2);   // A2: cols 0-127 agg, 128-255 h1
    u16* h2       = (u16*)alloc((size_t)NN * 256 * 2);
    u32* G1       = (u32*)alloc((size_t)4 * NN * 16 * 4);  // slice-major x_bf
    u32* G2       = (u32*)alloc((size_t)4 * NN * 16 * 4);  // slice-major h1
    u32* G3       = (u32*)alloc((size_t)4 * NN * 16 * 4);  // slice-major t3
    u16* o3       = (u16*)alloc((size_t)NN * 128 * 2);     // row-major o3
    u16* h3       = (u16*)alloc((size_t)NN * 128 * 2);     // row-major h3 (bf16)
    u16* BT1      = (u16*)alloc(128 * 256 * 2);
    u16* BT2      = (u16*)alloc(256 * 256 * 2);
    u16* BT3      = (u16*)alloc(256 * 256 * 2);
    float* bias3  = (float*)alloc(256 * sizeof(float));
    // pairs (12.85 MB) overlays h2 (25.6 MB): pairs lifetime ends at bfill,
    // h2 first written at gemm2.
    u32* pairs = (u32*)h2;

    hipMemsetAsync(bcnt, 0, 256 * sizeof(int), stream);

    // CSR pass 1 + x->bf16 (row + slice) + weight prep
    bscatter_prep_kernel<<<SCBLKS + XBLKS + 256, 256, 0, stream>>>(
        ei, bcnt, pairs, x, ax, G1, Wr1, Wo1, Wr2, Wo2, Wr3, Wo3, br3,
        BT1, BT2, BT3, bias3);
    // CSR pass 2
    bfill_kernel<<<NB, 512, 0, stream>>>(pairs, bcnt, ofs, srcl);

    // conv1: agg(x) -> ax cols 0-127; gemm1 -> h1 (row into ah1 cols 128+, slice into G2)
    // grid: NN/16 node-groups x 4 slices = 12500 blocks; 4 waves x 4 nodes each
    pull_slice_kernel<<<NN / 4, 256, 0, stream>>>(G1, ofs, srcl, (u32*)ax, 128);
    gemm_bf_kernel<<<dim3(1, 391), 256, 0, stream>>>(ax, BT1, br1,
                                                     ah1, 256, 128, 0, (u16*)G2, 128, 1);
    // conv2: agg(h1) -> ah1 cols 0-127; gemm2 -> h2 (row-major only)
    pull_slice_kernel<<<NN / 4, 256, 0, stream>>>(G2, ofs, srcl, (u32*)ah1, 128);
    gemm_bf_kernel<<<dim3(2, 391), 256, 0, stream>>>(ah1, BT2, br2,
                                                     h2, 256, 0, 0, nullptr, 0, 1);
    // conv3: cols 0-127 (t3) -> G3 slice-major; cols 128-255 (o3+br3) -> o3 row-major
    gemm_bf_kernel<<<dim3(2, 391), 256, 0, stream>>>(h2, BT3, bias3,
                                                     o3, 128, -128, 128, (u16*)G3, 128, 0);
    // h3 = agg(t3) + o3  (bf16)
    pull3_slice_kernel<<<NN / 4, 256, 0, stream>>>(G3, ofs, srcl, (const u32*)o3, (u32*)h3);

    // fused mean pool + head
    pool_head_kernel<<<GG, 256, 0, stream>>>((const u32*)h3, batch, W1, b1, W2, b2, out);
}

// Round 12
// 390.193 us; speedup vs baseline: 1.2060x; 1.0196x over previous
//
#include <hip/hip_runtime.h>
#include <hip/hip_bf16.h>
#include <cstddef>

#define NN 50000
#define EE 1600000
#define GG 512
#define NB 196        // ceil(NN/256) buckets of 256 nodes
#define BSTRIDE 16384 // fixed pairs-region capacity per bucket (max span ~8600)
#define BCAP 10240    // LDS staging per bucket
#define XBLKS 6250    // NN*32/256 x-convert blocks
#define SCBLKS 782    // ceil(EE/2048) bscatter blocks

typedef unsigned int u32;
typedef unsigned short u16;
typedef __attribute__((ext_vector_type(8))) short frag_ab;   // 8 bf16 = 4 VGPRs
typedef __attribute__((ext_vector_type(4))) float frag_cd;   // 4 fp32 acc

__device__ __forceinline__ void gl_lds16(const void* g, void* l) {
    __builtin_amdgcn_global_load_lds(
        (const __attribute__((address_space(1))) u32*)g,
        (__attribute__((address_space(3))) u32*)l, 16, 0, 0);
}
__device__ __forceinline__ float b2f_lo(u32 v) { return __uint_as_float(v << 16); }
__device__ __forceinline__ float b2f_hi(u32 v) { return __uint_as_float(v & 0xffff0000u); }
__device__ __forceinline__ float b2f(u32 v, int odd) { return odd ? b2f_hi(v) : b2f_lo(v); }
__device__ __forceinline__ u16 f2b(float x) {
    __hip_bfloat16 h = __float2bfloat16(x);
    return *(u16*)&h;
}
__device__ __forceinline__ u32 pack2(float lo, float hi) {
    return ((u32)f2b(hi) << 16) | f2b(lo);
}
__device__ __forceinline__ void acc2(float2& a, u32 v) {
    a.x += b2f_lo(v);
    a.y += b2f_hi(v);
}

// ---------------- fused: edge bucket-scatter + x->bf16 (row+slice) + weight prep ----------------

__global__ __launch_bounds__(256) void bscatter_prep_kernel(
    const int* __restrict__ ei, int* __restrict__ bcnt, u32* __restrict__ pairs,
    const float* __restrict__ x, u16* __restrict__ ax, u32* __restrict__ G1,
    const float* __restrict__ Wr1, const float* __restrict__ Wo1,
    const float* __restrict__ Wr2, const float* __restrict__ Wo2,
    const float* __restrict__ Wr3, const float* __restrict__ Wo3,
    const float* __restrict__ br3,
    u16* __restrict__ BT1, u16* __restrict__ BT2, u16* __restrict__ BT3,
    float* __restrict__ bias3) {
    __shared__ int lcnt[NB];
    __shared__ int lbase[NB];
    __shared__ unsigned short lpos[2048];
    int bid = blockIdx.x, t = threadIdx.x;
    if (bid < SCBLKS) {
        int e0 = bid * 2048;
        u32 pk[8];   // packed (src<<8)|(dst&255) stashed across phases
        int bk[8];
        for (int i = t; i < NB; i += 256) lcnt[i] = 0;
        __syncthreads();
#pragma unroll
        for (int i = 0; i < 8; ++i) {
            int e = e0 + i * 256 + t;
            if (e < EE) {
                int dst = ei[EE + e], src = ei[e];
                int b = dst >> 8;
                bk[i] = b;
                pk[i] = ((u32)src << 8) | (u32)(dst & 255);
                lpos[i * 256 + t] = (unsigned short)atomicAdd(&lcnt[b], 1);
            } else bk[i] = -1;
        }
        __syncthreads();
        for (int i = t; i < NB; i += 256) lbase[i] = atomicAdd(&bcnt[i], lcnt[i]);
        __syncthreads();
#pragma unroll
        for (int i = 0; i < 8; ++i) {
            if (bk[i] >= 0) {
                int pos = lbase[bk[i]] + (int)lpos[i * 256 + t];
                pairs[(size_t)bk[i] * BSTRIDE + pos] = pk[i];
            }
        }
    } else if (bid < SCBLKS + XBLKS) {
        int idx = (bid - SCBLKS) * 256 + t;
        int row = idx >> 5, q = idx & 31;     // q: 4-float group (u32 words 2q, 2q+1)
        float4 v = *(const float4*)(x + (size_t)row * 128 + q * 4);
        u32 w0 = pack2(v.x, v.y), w1 = pack2(v.z, v.w);
        // row-major (GEMM A cols 128..255)
        *(u32*)(ax + (size_t)row * 256 + 128 + q * 4) = w0;
        *(u32*)(ax + (size_t)row * 256 + 128 + q * 4 + 2) = w1;
        // slice-major gather copy: slice = q>>3, word-in-slice = (2q)&15
        uint2 r; r.x = w0; r.y = w1;
        *(uint2*)(G1 + ((size_t)(q >> 3) * NN + row) * 16 + ((2 * q) & 15)) = r;
    } else {
        int m = bid - SCBLKS - XBLKS;   // 0..255 output col
        int k = t;                       // reduction idx
        BT2[m * 256 + k] = f2b(k < 128 ? Wr2[k * 256 + m] : Wo2[(k - 128) * 256 + m]);
        BT3[m * 256 + k] = f2b(m < 128 ? Wr3[k * 128 + m] : Wo3[k * 128 + (m - 128)]);
        if (m < 128)
            BT1[m * 256 + k] = f2b(k < 128 ? Wr1[k * 128 + m] : Wo1[(k - 128) * 128 + m]);
        if (k == 0) bias3[m] = (m < 128) ? 0.f : br3[m - 128];
    }
}

// ---------------- CSR pass 2 (512 threads/block; srcl in u16) ----------------

__global__ __launch_bounds__(512) void bfill_kernel(const u32* __restrict__ pairs,
                                                    const int* __restrict__ bcnt,
                                                    int* __restrict__ ofs,
                                                    u16* __restrict__ srcl) {
    __shared__ int sc[256];
    __shared__ int cnts[256];
    __shared__ int lcnt[256];
    __shared__ int lcur[256];
    __shared__ int lbuf[BCAP];
    int b = blockIdx.x, t = threadIdx.x;
    if (t < 256) {
        int c = (t < NB) ? bcnt[t] : 0;
        cnts[t] = c;
        sc[t] = c;
        lcnt[t] = 0;
    }
    __syncthreads();
    for (int off = 1; off < 256; off <<= 1) {
        int v = (t >= off && t < 256) ? sc[t - off] : 0;
        __syncthreads();
        if (t < 256) sc[t] += v;
        __syncthreads();
    }
    int base = sc[b] - cnts[b];
    int span = cnts[b];
    const u32* pp = pairs + (size_t)b * BSTRIDE;
    for (int j = t; j < span; j += 512) atomicAdd(&lcnt[pp[j] & 255u], 1);
    __syncthreads();
    int nc = 0;
    if (t < 256) {
        nc = lcnt[t];
        sc[t] = nc;
    }
    __syncthreads();
    for (int off = 1; off < 256; off <<= 1) {
        int v = (t >= off && t < 256) ? sc[t - off] : 0;
        __syncthreads();
        if (t < 256) sc[t] += v;
        __syncthreads();
    }
    if (t < 256) {
        int excl = sc[t] - nc;
        int node = b * 256 + t;
        if (node < NN) ofs[node] = base + excl;
        lcur[t] = excl;
    }
    if (b == 0 && t == 256) ofs[NN] = EE;
    __syncthreads();
    for (int j = t; j < span; j += 512) {
        u32 p = pp[j];
        int pos = atomicAdd(&lcur[p & 255u], 1);
        int src = (int)(p >> 8);
        if (pos < BCAP) lbuf[pos] = src;
        else srcl[base + pos] = (u16)src;
    }
    __syncthreads();
    int lim = span < BCAP ? span : BCAP;
    for (int j = t; j < lim; j += 512) srcl[base + j] = (u16)lbuf[j];
}

// ---------------- slice-major pull, v4: 4 nodes/wave, 8 loads in flight ----------------
// G: [4][NN][16] u32. slice = blockIdx&3 (XCD-pinned via %8 round-robin).
// Wave: nd=lane>>4 (node), eq=(lane>>2)&3 (edge slot), wg=lane&3 (uint4 word
// group). Iter = 32 edges/node: phase 1 fills v[8] (guarded, zero-init) so all
// 8 global_load_dwordx4 are issued before any use; phase 2 accumulates.

__global__ __launch_bounds__(256) void pull_slice_kernel(const u32* __restrict__ G,
                                                         const int* __restrict__ ofs,
                                                         const u16* __restrict__ srcl,
                                                         u32* __restrict__ outu,
                                                         int rowstride) {
    int s = blockIdx.x & 3;
    int lane = threadIdx.x & 63;
    int node = (blockIdx.x >> 2) * 16 + ((threadIdx.x >> 6) << 2) + (lane >> 4);
    int eq = (lane >> 2) & 3, wg = lane & 3;
    const u32* Gs = G + (size_t)s * NN * 16;
    int lo = ofs[node], hi = ofs[node + 1];
    float2 a0 = {0.f, 0.f}, a1 = {0.f, 0.f}, a2 = {0.f, 0.f}, a3 = {0.f, 0.f};
    int j = lo + eq;
    while (__any(j < hi)) {
        uint4 v[8];
#pragma unroll
        for (int u = 0; u < 8; ++u) {
            v[u] = make_uint4(0u, 0u, 0u, 0u);
            if (j + u * 4 < hi) {
                int s0 = srcl[j + u * 4];
                v[u] = *(const uint4*)(Gs + (size_t)s0 * 16 + wg * 4);
            }
        }
#pragma unroll
        for (int u = 0; u < 8; ++u) {
            acc2(a0, v[u].x); acc2(a1, v[u].y); acc2(a2, v[u].z); acc2(a3, v[u].w);
        }
        j += 32;
    }
    float acc[8] = {a0.x, a0.y, a1.x, a1.y, a2.x, a2.y, a3.x, a3.y};
#pragma unroll
    for (int i = 0; i < 8; ++i) {
        acc[i] += __shfl_xor(acc[i], 4, 64);
        acc[i] += __shfl_xor(acc[i], 8, 64);
    }
    if (eq == 0) {
        uint4 r;
        r.x = pack2(acc[0], acc[1]);
        r.y = pack2(acc[2], acc[3]);
        r.z = pack2(acc[4], acc[5]);
        r.w = pack2(acc[6], acc[7]);
        *(uint4*)(outu + (size_t)node * rowstride + s * 16 + wg * 4) = r;
    }
}

// pull3: gather G3 (t3, slice-major) + add o3 (row-major [NN][64]u32) -> h3 [NN][64]u32.
__global__ __launch_bounds__(256) void pull3_slice_kernel(const u32* __restrict__ G,
                                                          const int* __restrict__ ofs,
                                                          const u16* __restrict__ srcl,
                                                          const u32* __restrict__ o3u,
                                                          u32* __restrict__ h3u) {
    int s = blockIdx.x & 3;
    int lane = threadIdx.x & 63;
    int node = (blockIdx.x >> 2) * 16 + ((threadIdx.x >> 6) << 2) + (lane >> 4);
    int eq = (lane >> 2) & 3, wg = lane & 3;
    const u32* Gs = G + (size_t)s * NN * 16;
    int lo = ofs[node], hi = ofs[node + 1];
    float2 a0 = {0.f, 0.f}, a1 = {0.f, 0.f}, a2 = {0.f, 0.f}, a3 = {0.f, 0.f};
    int j = lo + eq;
    while (__any(j < hi)) {
        uint4 v[8];
#pragma unroll
        for (int u = 0; u < 8; ++u) {
            v[u] = make_uint4(0u, 0u, 0u, 0u);
            if (j + u * 4 < hi) {
                int s0 = srcl[j + u * 4];
                v[u] = *(const uint4*)(Gs + (size_t)s0 * 16 + wg * 4);
            }
        }
#pragma unroll
        for (int u = 0; u < 8; ++u) {
            acc2(a0, v[u].x); acc2(a1, v[u].y); acc2(a2, v[u].z); acc2(a3, v[u].w);
        }
        j += 32;
    }
    float acc[8] = {a0.x, a0.y, a1.x, a1.y, a2.x, a2.y, a3.x, a3.y};
#pragma unroll
    for (int i = 0; i < 8; ++i) {
        acc[i] += __shfl_xor(acc[i], 4, 64);
        acc[i] += __shfl_xor(acc[i], 8, 64);
    }
    if (eq == 0) {
        uint4 o = *(const uint4*)(o3u + (size_t)node * 64 + s * 16 + wg * 4);
        acc[0] += b2f_lo(o.x); acc[1] += b2f_hi(o.x);
        acc[2] += b2f_lo(o.y); acc[3] += b2f_hi(o.y);
        acc[4] += b2f_lo(o.z); acc[5] += b2f_hi(o.z);
        acc[6] += b2f_lo(o.w); acc[7] += b2f_hi(o.w);
        uint4 r;
        r.x = pack2(acc[0], acc[1]);
        r.y = pack2(acc[2], acc[3]);
        r.z = pack2(acc[4], acc[5]);
        r.w = pack2(acc[6], acc[7]);
        *(uint4*)(h3u + (size_t)node * 64 + s * 16 + wg * 4) = r;
    }
}

// ---------------- bf16 MFMA GEMM: K=256, flexible epilogue ----------------
// col >= rowlo -> Crow[(row*ldc)+coloff+col]; col < slchi -> slice-major Cslc.

__global__ __launch_bounds__(256, 2) void gemm_bf_kernel(
    const u16* __restrict__ A, const u16* __restrict__ BT,
    const float* __restrict__ bias, u16* __restrict__ Crow,
    int ldc, int coloff, int rowlo, u16* __restrict__ Cslc, int slchi, int relu) {
    __shared__ alignas(16) u16 As[128 * 32];
    __shared__ alignas(16) u16 Bs[128 * 32];
    const int t = threadIdx.x;
    const int lane = t & 63, wid = t >> 6;
    const int quad = lane >> 4, l16 = lane & 15;
    const int wm = wid >> 1, wn = wid & 1;
    const int row0 = blockIdx.y * 128, c0 = blockIdx.x * 128;

    frag_cd acc[4][4];
#pragma unroll
    for (int i = 0; i < 4; ++i)
#pragma unroll
        for (int j = 0; j < 4; ++j) acc[i][j] = (frag_cd)0.f;

    const int ca = t, cb = t + 256;
    const int ra = ca >> 2, oa = (ca & 3) * 8;
    const int rb = cb >> 2, ob = (cb & 3) * 8;
    const int garow = min(row0 + ra, NN - 1);
    const int gbrow = min(row0 + rb, NN - 1);
    const size_t gA1 = (size_t)garow * 256 + oa;
    const size_t gA2 = (size_t)gbrow * 256 + ob;
    const size_t gB1 = (size_t)(c0 + ra) * 256 + oa;
    const size_t gB2 = (size_t)(c0 + rb) * 256 + ob;

    for (int kk = 0; kk < 256; kk += 32) {
        __syncthreads();
        gl_lds16(A + gA1 + kk, &As[ca * 8]);
        gl_lds16(A + gA2 + kk, &As[cb * 8]);
        gl_lds16(BT + gB1 + kk, &Bs[ca * 8]);
        gl_lds16(BT + gB2 + kk, &Bs[cb * 8]);
        __syncthreads();

        frag_ab a[4], b[4];
#pragma unroll
        for (int mt = 0; mt < 4; ++mt)
            a[mt] = *(const frag_ab*)&As[(wm * 64 + mt * 16 + l16) * 32 + quad * 8];
#pragma unroll
        for (int nt = 0; nt < 4; ++nt)
            b[nt] = *(const frag_ab*)&Bs[(wn * 64 + nt * 16 + l16) * 32 + quad * 8];
#pragma unroll
        for (int mt = 0; mt < 4; ++mt)
#pragma unroll
            for (int nt = 0; nt < 4; ++nt)
                acc[mt][nt] = __builtin_amdgcn_mfma_f32_16x16x32_bf16(
                    a[mt], b[nt], acc[mt][nt], 0, 0, 0);
    }

#pragma unroll
    for (int nt = 0; nt < 4; ++nt) {
        int col = c0 + wn * 64 + nt * 16 + l16;
        float bv = bias[col];
        int w = col >> 1, s = w >> 4, wis = w & 15, odd = col & 1;
#pragma unroll
        for (int mt = 0; mt < 4; ++mt) {
#pragma unroll
            for (int r = 0; r < 4; ++r) {
                int row = row0 + wm * 64 + mt * 16 + quad * 4 + r;
                if (row < NN) {
                    float v = acc[mt][nt][r] + bv;
                    if (relu) v = fmaxf(v, 0.f);
                    u16 bb = f2b(v);
                    if (col >= rowlo)
                        Crow[(size_t)row * ldc + coloff + col] = bb;
                    if (col < slchi)
                        Cslc[(((size_t)s * NN + row) * 16 + wis) * 2 + odd] = bb;
                }
            }
        }
    }
}

// ---------------- fused mean-pool + head (4 waves, unrolled scan) ----------------

__device__ inline int lower_bound_i(const int* a, int n, int v) {
    int lo = 0, hi = n;
    while (lo < hi) {
        int m = (lo + hi) >> 1;
        if (a[m] < v) lo = m + 1; else hi = m;
    }
    return lo;
}

__global__ __launch_bounds__(256) void pool_head_kernel(const u32* __restrict__ h3u,
                                                        const int* __restrict__ batch,
                                                        const float* __restrict__ W1,
                                                        const float* __restrict__ b1,
                                                        const float* __restrict__ W2,
                                                        const float* __restrict__ b2,
                                                        float* __restrict__ out) {
    __shared__ float ps[256];
    __shared__ float p[128];
    __shared__ float hid[40];
    int g = blockIdx.x, t = threadIdx.x;
    int c = t & 127, half = t >> 7;        // 2 row-groups x 128 channels
    int w = c >> 1, odd = c & 1;
    int lo = lower_bound_i(batch, NN, g);
    int hi = lower_bound_i(batch, NN, g + 1);
    float s = 0.f;
    int i = lo + half;
    for (; i + 6 < hi; i += 8) {           // 4 independent loads in flight
        u32 v0 = h3u[(size_t)i * 64 + w];
        u32 v1 = h3u[(size_t)(i + 2) * 64 + w];
        u32 v2 = h3u[(size_t)(i + 4) * 64 + w];
        u32 v3 = h3u[(size_t)(i + 6) * 64 + w];
        s += (b2f(v0, odd) + b2f(v1, odd)) + (b2f(v2, odd) + b2f(v3, odd));
    }
    for (; i < hi; i += 2) s += b2f(h3u[(size_t)i * 64 + w], odd);
    ps[t] = s;
    __syncthreads();
    if (half == 0) p[c] = (ps[c] + ps[c + 128]) / fmaxf((float)(hi - lo), 1.f);
    __syncthreads();
    if (t < 40) {
        float v = b1[t];
        for (int k = 0; k < 128; ++k) v += p[k] * W1[k * 40 + t];
        hid[t] = v;
    }
    __syncthreads();
    if (t < 10) {
        float v = b2[t];
        for (int j = 0; j < 40; ++j) v += hid[j] * W2[j * 10 + t];
        out[g * 10 + t] = v;
    }
}

// ---------------- launch ----------------

extern "C" void kernel_launch(void* const* d_in, const int* in_sizes, int n_in,
                              void* d_out, int out_size, void* d_ws, size_t ws_size,
                              hipStream_t stream) {
    const float* x   = (const float*)d_in[0];
    const int* ei    = (const int*)d_in[1];
    const int* batch = (const int*)d_in[2];
    const float* Wr1 = (const float*)d_in[3];
    const float* br1 = (const float*)d_in[4];
    const float* Wo1 = (const float*)d_in[5];
    const float* Wr2 = (const float*)d_in[6];
    const float* br2 = (const float*)d_in[7];
    const float* Wo2 = (const float*)d_in[8];
    const float* Wr3 = (const float*)d_in[9];
    const float* br3 = (const float*)d_in[10];
    const float* Wo3 = (const float*)d_in[11];
    const float* W1  = (const float*)d_in[12];
    const float* b1  = (const float*)d_in[13];
    const float* W2  = (const float*)d_in[14];
    const float* b2  = (const float*)d_in[15];
    float* out = (float*)d_out;

    char* ws = (char*)d_ws;
    size_t off = 0;
    auto alloc = [&](size_t bytes) {
        void* p = ws + off;
        off += (bytes + 255) & ~(size_t)255;
        return p;
    };
    int* ofs      = (int*)alloc((NN + 1) * sizeof(int));
    int* bcnt     = (int*)alloc(256 * sizeof(int));
    u16* srcl     = (u16*)alloc((size_t)EE * 2);
    u16* ax       = (u16*)alloc((size_t)NN * 256 * 2);   // A1: cols 0-127 agg, 128-255 x_bf
    u16* ah1      = (u16*)alloc((size_t)NN * 256 * 2);   // A2: cols 0-127 agg, 128-255 h1
    u16* h2       = (u16*)alloc((size_t)NN * 256 * 2);
    u32* G1       = (u32*)alloc((size_t)4 * NN * 16 * 4);  // slice-major x_bf
    u32* G2       = (u32*)alloc((size_t)4 * NN * 16 * 4);  // slice-major h1
    u32* G3       = (u32*)alloc((size_t)4 * NN * 16 * 4);  // slice-major t3
    u16* o3       = (u16*)alloc((size_t)NN * 128 * 2);     // row-major o3
    u16* h3       = (u16*)alloc((size_t)NN * 128 * 2);     // row-major h3 (bf16)
    u16* BT1      = (u16*)alloc(128 * 256 * 2);
    u16* BT2      = (u16*)alloc(256 * 256 * 2);
    u16* BT3      = (u16*)alloc(256 * 256 * 2);
    float* bias3  = (float*)alloc(256 * sizeof(float));
    // pairs (12.85 MB) overlays h2 (25.6 MB): pairs lifetime ends at bfill,
    // h2 first written at gemm2.
    u32* pairs = (u32*)h2;

    hipMemsetAsync(bcnt, 0, 256 * sizeof(int), stream);

    // CSR pass 1 + x->bf16 (row + slice) + weight prep
    bscatter_prep_kernel<<<SCBLKS + XBLKS + 256, 256, 0, stream>>>(
        ei, bcnt, pairs, x, ax, G1, Wr1, Wo1, Wr2, Wo2, Wr3, Wo3, br3,
        BT1, BT2, BT3, bias3);
    // CSR pass 2
    bfill_kernel<<<NB, 512, 0, stream>>>(pairs, bcnt, ofs, srcl);

    // conv1: agg(x) -> ax cols 0-127; gemm1 -> h1 (row into ah1 cols 128+, slice into G2)
    pull_slice_kernel<<<NN / 4, 256, 0, stream>>>(G1, ofs, srcl, (u32*)ax, 128);
    gemm_bf_kernel<<<dim3(1, 391), 256, 0, stream>>>(ax, BT1, br1,
                                                     ah1, 256, 128, 0, (u16*)G2, 128, 1);
    // conv2: agg(h1) -> ah1 cols 0-127; gemm2 -> h2 (row-major only)
    pull_slice_kernel<<<NN / 4, 256, 0, stream>>>(G2, ofs, srcl, (u32*)ah1, 128);
    gemm_bf_kernel<<<dim3(2, 391), 256, 0, stream>>>(ah1, BT2, br2,
                                                     h2, 256, 0, 0, nullptr, 0, 1);
    // conv3: cols 0-127 (t3) -> G3 slice-major; cols 128-255 (o3+br3) -> o3 row-major
    gemm_bf_kernel<<<dim3(2, 391), 256, 0, stream>>>(h2, BT3, bias3,
                                                     o3, 128, -128, 128, (u16*)G3, 128, 0);
    // h3 = agg(t3) + o3  (bf16)
    pull3_slice_kernel<<<NN / 4, 256, 0, stream>>>(G3, ofs, srcl, (const u32*)o3, (u32*)h3);

    // fused mean pool + head
    pool_head_kernel<<<GG, 256, 0, stream>>>((const u32*)h3, batch, W1, b1, W2, b2, out);
}

// Round 13
// 360.133 us; speedup vs baseline: 1.3067x; 1.0835x over previous
//
#include <hip/hip_runtime.h>
#include <hip/hip_bf16.h>
#include <cstddef>

#define NN 50000
#define EE 1600000
#define GG 512
#define NB 196        // ceil(NN/256) buckets of 256 nodes
#define BSTRIDE 16384 // fixed pairs-region capacity per bucket (max span ~8600)
#define BCAP 10240    // LDS staging per bucket
#define XBLKS 6250    // NN*32/256 x-convert blocks
#define SCBLKS 782    // ceil(EE/2048) bscatter blocks

typedef unsigned int u32;
typedef unsigned short u16;
typedef __attribute__((ext_vector_type(8))) short frag_ab;   // 8 bf16 = 4 VGPRs
typedef __attribute__((ext_vector_type(4))) float frag_cd;   // 4 fp32 acc

__device__ __forceinline__ void gl_lds16(const void* g, void* l) {
    __builtin_amdgcn_global_load_lds(
        (const __attribute__((address_space(1))) u32*)g,
        (__attribute__((address_space(3))) u32*)l, 16, 0, 0);
}
__device__ __forceinline__ float b2f_lo(u32 v) { return __uint_as_float(v << 16); }
__device__ __forceinline__ float b2f_hi(u32 v) { return __uint_as_float(v & 0xffff0000u); }
__device__ __forceinline__ float b2f(u32 v, int odd) { return odd ? b2f_hi(v) : b2f_lo(v); }
__device__ __forceinline__ u16 f2b(float x) {
    __hip_bfloat16 h = __float2bfloat16(x);
    return *(u16*)&h;
}
__device__ __forceinline__ u32 pack2(float lo, float hi) {
    return ((u32)f2b(hi) << 16) | f2b(lo);
}
__device__ __forceinline__ void acc2(float2& a, u32 v) {
    a.x += b2f_lo(v);
    a.y += b2f_hi(v);
}

// ---------------- fused: edge bucket-scatter + x->bf16 + weight prep ----------------

__global__ __launch_bounds__(256) void bscatter_prep_kernel(
    const int* __restrict__ ei, int* __restrict__ bcnt, u32* __restrict__ pairs,
    const float* __restrict__ x, u16* __restrict__ ax,
    const float* __restrict__ Wr1, const float* __restrict__ Wo1,
    const float* __restrict__ Wr2, const float* __restrict__ Wo2,
    const float* __restrict__ Wr3, const float* __restrict__ Wo3,
    const float* __restrict__ br3,
    u16* __restrict__ BT1, u16* __restrict__ BT2, u16* __restrict__ BT3,
    float* __restrict__ bias3) {
    __shared__ int lcnt[NB];
    __shared__ int lbase[NB];
    __shared__ unsigned short lpos[2048];
    int bid = blockIdx.x, t = threadIdx.x;
    if (bid < SCBLKS) {
        int e0 = bid * 2048;
        u32 pk[8];   // packed (src<<8)|(dst&255) stashed across phases
        int bk[8];
        for (int i = t; i < NB; i += 256) lcnt[i] = 0;
        __syncthreads();
#pragma unroll
        for (int i = 0; i < 8; ++i) {
            int e = e0 + i * 256 + t;
            if (e < EE) {
                int dst = ei[EE + e], src = ei[e];
                int b = dst >> 8;
                bk[i] = b;
                pk[i] = ((u32)src << 8) | (u32)(dst & 255);
                lpos[i * 256 + t] = (unsigned short)atomicAdd(&lcnt[b], 1);
            } else bk[i] = -1;
        }
        __syncthreads();
        for (int i = t; i < NB; i += 256) lbase[i] = atomicAdd(&bcnt[i], lcnt[i]);
        __syncthreads();
#pragma unroll
        for (int i = 0; i < 8; ++i) {
            if (bk[i] >= 0) {
                int pos = lbase[bk[i]] + (int)lpos[i * 256 + t];
                pairs[(size_t)bk[i] * BSTRIDE + pos] = pk[i];
            }
        }
    } else if (bid < SCBLKS + XBLKS) {
        int idx = (bid - SCBLKS) * 256 + t;
        int row = idx >> 5, q = idx & 31;
        float4 v = *(const float4*)(x + (size_t)row * 128 + q * 4);
        *(u32*)(ax + (size_t)row * 256 + 128 + q * 4) = pack2(v.x, v.y);
        *(u32*)(ax + (size_t)row * 256 + 128 + q * 4 + 2) = pack2(v.z, v.w);
    } else {
        int m = bid - SCBLKS - XBLKS;   // 0..255 output col
        int k = t;                       // reduction idx
        BT2[m * 256 + k] = f2b(k < 128 ? Wr2[k * 256 + m] : Wo2[(k - 128) * 256 + m]);
        BT3[m * 256 + k] = f2b(m < 128 ? Wr3[k * 128 + m] : Wo3[k * 128 + (m - 128)]);
        if (m < 128)
            BT1[m * 256 + k] = f2b(k < 128 ? Wr1[k * 128 + m] : Wo1[(k - 128) * 128 + m]);
        if (k == 0) bias3[m] = (m < 128) ? 0.f : br3[m - 128];
    }
}

// ---------------- CSR pass 2 (512 threads/block; srcl in u16) ----------------

__global__ __launch_bounds__(512) void bfill_kernel(const u32* __restrict__ pairs,
                                                    const int* __restrict__ bcnt,
                                                    int* __restrict__ ofs,
                                                    u16* __restrict__ srcl) {
    __shared__ int sc[256];
    __shared__ int cnts[256];
    __shared__ int lcnt[256];
    __shared__ int lcur[256];
    __shared__ int lbuf[BCAP];
    int b = blockIdx.x, t = threadIdx.x;
    if (t < 256) {
        int c = (t < NB) ? bcnt[t] : 0;
        cnts[t] = c;
        sc[t] = c;
        lcnt[t] = 0;
    }
    __syncthreads();
    for (int off = 1; off < 256; off <<= 1) {
        int v = (t >= off && t < 256) ? sc[t - off] : 0;
        __syncthreads();
        if (t < 256) sc[t] += v;
        __syncthreads();
    }
    int base = sc[b] - cnts[b];
    int span = cnts[b];
    const u32* pp = pairs + (size_t)b * BSTRIDE;
    for (int j = t; j < span; j += 512) atomicAdd(&lcnt[pp[j] & 255u], 1);
    __syncthreads();
    int nc = 0;
    if (t < 256) {
        nc = lcnt[t];
        sc[t] = nc;
    }
    __syncthreads();
    for (int off = 1; off < 256; off <<= 1) {
        int v = (t >= off && t < 256) ? sc[t - off] : 0;
        __syncthreads();
        if (t < 256) sc[t] += v;
        __syncthreads();
    }
    if (t < 256) {
        int excl = sc[t] - nc;
        int node = b * 256 + t;
        if (node < NN) ofs[node] = base + excl;
        lcur[t] = excl;
    }
    if (b == 0 && t == 256) ofs[NN] = EE;
    __syncthreads();
    for (int j = t; j < span; j += 512) {
        u32 p = pp[j];
        int pos = atomicAdd(&lcur[p & 255u], 1);
        int src = (int)(p >> 8);
        if (pos < BCAP) lbuf[pos] = src;
        else srcl[base + pos] = (u16)src;
    }
    __syncthreads();
    int lim = span < BCAP ? span : BCAP;
    for (int j = t; j < lim; j += 512) srcl[base + j] = (u16)lbuf[j];
}

// ---------------- bf16 pull, row-major, wide-load, 16-edge unroll (R8 proven) ----
// One wave per node. q=lane>>4: edge slot; l=lane&15: channel group (8 ch, dwordx4).
// Fetch-bound at the L2-fill fabric (~155 MB @ ~3.4 TB/s): structural floor.

__global__ __launch_bounds__(256) void pull_bf_kernel(const u32* __restrict__ Xu,
                                                      const int* __restrict__ ofs,
                                                      const u16* __restrict__ srcl,
                                                      u32* __restrict__ outu) {
    int node = (blockIdx.x * 256 + threadIdx.x) >> 6;
    int lane = threadIdx.x & 63;
    int q = lane >> 4, l = lane & 15;
    int lo = ofs[node], hi = ofs[node + 1];
    float2 a0 = {0.f, 0.f}, a1 = {0.f, 0.f}, a2 = {0.f, 0.f}, a3 = {0.f, 0.f};
    int j = lo;
    for (; j + 15 < hi; j += 16) {
        int s0 = srcl[j + q], s1 = srcl[j + 4 + q];
        int s2 = srcl[j + 8 + q], s3 = srcl[j + 12 + q];
        uint4 v0 = *(const uint4*)(Xu + (size_t)s0 * 128 + l * 4);
        uint4 v1 = *(const uint4*)(Xu + (size_t)s1 * 128 + l * 4);
        uint4 v2 = *(const uint4*)(Xu + (size_t)s2 * 128 + l * 4);
        uint4 v3 = *(const uint4*)(Xu + (size_t)s3 * 128 + l * 4);
        acc2(a0, v0.x); acc2(a1, v0.y); acc2(a2, v0.z); acc2(a3, v0.w);
        acc2(a0, v1.x); acc2(a1, v1.y); acc2(a2, v1.z); acc2(a3, v1.w);
        acc2(a0, v2.x); acc2(a1, v2.y); acc2(a2, v2.z); acc2(a3, v2.w);
        acc2(a0, v3.x); acc2(a1, v3.y); acc2(a2, v3.z); acc2(a3, v3.w);
    }
    for (; j + 3 < hi; j += 4) {
        int s = srcl[j + q];
        uint4 v = *(const uint4*)(Xu + (size_t)s * 128 + l * 4);
        acc2(a0, v.x); acc2(a1, v.y); acc2(a2, v.z); acc2(a3, v.w);
    }
    if (j + q < hi) {
        int s = srcl[j + q];
        uint4 v = *(const uint4*)(Xu + (size_t)s * 128 + l * 4);
        acc2(a0, v.x); acc2(a1, v.y); acc2(a2, v.z); acc2(a3, v.w);
    }
    float acc[8] = {a0.x, a0.y, a1.x, a1.y, a2.x, a2.y, a3.x, a3.y};
#pragma unroll
    for (int i = 0; i < 8; ++i) {
        acc[i] += __shfl_xor(acc[i], 16, 64);
        acc[i] += __shfl_xor(acc[i], 32, 64);
    }
    if (q == 0) {
        uint4 r;
        r.x = pack2(acc[0], acc[1]);
        r.y = pack2(acc[2], acc[3]);
        r.z = pack2(acc[4], acc[5]);
        r.w = pack2(acc[6], acc[7]);
        *(uint4*)(outu + (size_t)node * 128 + l * 4) = r;
    }
}

// pull3: gather t3 (cols 0..127) + add o3 (cols 128..255), bf16 h3 out (stride 64 u32).
__global__ __launch_bounds__(256) void pull3_kernel(const u32* __restrict__ Tu,
                                                    const int* __restrict__ ofs,
                                                    const u16* __restrict__ srcl,
                                                    u32* __restrict__ h3u) {
    int node = (blockIdx.x * 256 + threadIdx.x) >> 6;
    int lane = threadIdx.x & 63;
    int q = lane >> 4, l = lane & 15;
    int lo = ofs[node], hi = ofs[node + 1];
    float2 a0 = {0.f, 0.f}, a1 = {0.f, 0.f}, a2 = {0.f, 0.f}, a3 = {0.f, 0.f};
    int j = lo;
    for (; j + 15 < hi; j += 16) {
        int s0 = srcl[j + q], s1 = srcl[j + 4 + q];
        int s2 = srcl[j + 8 + q], s3 = srcl[j + 12 + q];
        uint4 v0 = *(const uint4*)(Tu + (size_t)s0 * 128 + l * 4);
        uint4 v1 = *(const uint4*)(Tu + (size_t)s1 * 128 + l * 4);
        uint4 v2 = *(const uint4*)(Tu + (size_t)s2 * 128 + l * 4);
        uint4 v3 = *(const uint4*)(Tu + (size_t)s3 * 128 + l * 4);
        acc2(a0, v0.x); acc2(a1, v0.y); acc2(a2, v0.z); acc2(a3, v0.w);
        acc2(a0, v1.x); acc2(a1, v1.y); acc2(a2, v1.z); acc2(a3, v1.w);
        acc2(a0, v2.x); acc2(a1, v2.y); acc2(a2, v2.z); acc2(a3, v2.w);
        acc2(a0, v3.x); acc2(a1, v3.y); acc2(a2, v3.z); acc2(a3, v3.w);
    }
    for (; j + 3 < hi; j += 4) {
        int s = srcl[j + q];
        uint4 v = *(const uint4*)(Tu + (size_t)s * 128 + l * 4);
        acc2(a0, v.x); acc2(a1, v.y); acc2(a2, v.z); acc2(a3, v.w);
    }
    if (j + q < hi) {
        int s = srcl[j + q];
        uint4 v = *(const uint4*)(Tu + (size_t)s * 128 + l * 4);
        acc2(a0, v.x); acc2(a1, v.y); acc2(a2, v.z); acc2(a3, v.w);
    }
    float acc[8] = {a0.x, a0.y, a1.x, a1.y, a2.x, a2.y, a3.x, a3.y};
#pragma unroll
    for (int i = 0; i < 8; ++i) {
        acc[i] += __shfl_xor(acc[i], 16, 64);
        acc[i] += __shfl_xor(acc[i], 32, 64);
    }
    if (q == 0) {
        uint4 o = *(const uint4*)(Tu + (size_t)node * 128 + 64 + l * 4);
        acc[0] += b2f_lo(o.x); acc[1] += b2f_hi(o.x);
        acc[2] += b2f_lo(o.y); acc[3] += b2f_hi(o.y);
        acc[4] += b2f_lo(o.z); acc[5] += b2f_hi(o.z);
        acc[6] += b2f_lo(o.w); acc[7] += b2f_hi(o.w);
        uint4 r;
        r.x = pack2(acc[0], acc[1]);
        r.y = pack2(acc[2], acc[3]);
        r.z = pack2(acc[4], acc[5]);
        r.w = pack2(acc[6], acc[7]);
        *(uint4*)(h3u + (size_t)node * 64 + l * 4) = r;
    }
}

// ---------------- bf16 MFMA GEMM: C = relu?(A @ BT^T + bias), K=256 ----------------

__global__ __launch_bounds__(256, 2) void gemm_bf_kernel(
    const u16* __restrict__ A, const u16* __restrict__ BT,
    const float* __restrict__ bias, u16* __restrict__ C,
    int ldc, int coloff, int relu) {
    __shared__ alignas(16) u16 As[128 * 32];
    __shared__ alignas(16) u16 Bs[128 * 32];
    const int t = threadIdx.x;
    const int lane = t & 63, wid = t >> 6;
    const int quad = lane >> 4, l16 = lane & 15;
    const int wm = wid >> 1, wn = wid & 1;
    const int row0 = blockIdx.y * 128, c0 = blockIdx.x * 128;

    frag_cd acc[4][4];
#pragma unroll
    for (int i = 0; i < 4; ++i)
#pragma unroll
        for (int j = 0; j < 4; ++j) acc[i][j] = (frag_cd)0.f;

    const int ca = t, cb = t + 256;
    const int ra = ca >> 2, oa = (ca & 3) * 8;
    const int rb = cb >> 2, ob = (cb & 3) * 8;
    const int garow = min(row0 + ra, NN - 1);
    const int gbrow = min(row0 + rb, NN - 1);
    const size_t gA1 = (size_t)garow * 256 + oa;
    const size_t gA2 = (size_t)gbrow * 256 + ob;
    const size_t gB1 = (size_t)(c0 + ra) * 256 + oa;
    const size_t gB2 = (size_t)(c0 + rb) * 256 + ob;

    for (int kk = 0; kk < 256; kk += 32) {
        __syncthreads();
        gl_lds16(A + gA1 + kk, &As[ca * 8]);
        gl_lds16(A + gA2 + kk, &As[cb * 8]);
        gl_lds16(BT + gB1 + kk, &Bs[ca * 8]);
        gl_lds16(BT + gB2 + kk, &Bs[cb * 8]);
        __syncthreads();

        frag_ab a[4], b[4];
#pragma unroll
        for (int mt = 0; mt < 4; ++mt)
            a[mt] = *(const frag_ab*)&As[(wm * 64 + mt * 16 + l16) * 32 + quad * 8];
#pragma unroll
        for (int nt = 0; nt < 4; ++nt)
            b[nt] = *(const frag_ab*)&Bs[(wn * 64 + nt * 16 + l16) * 32 + quad * 8];
#pragma unroll
        for (int mt = 0; mt < 4; ++mt)
#pragma unroll
            for (int nt = 0; nt < 4; ++nt)
                acc[mt][nt] = __builtin_amdgcn_mfma_f32_16x16x32_bf16(
                    a[mt], b[nt], acc[mt][nt], 0, 0, 0);
    }

#pragma unroll
    for (int nt = 0; nt < 4; ++nt) {
        int col = c0 + wn * 64 + nt * 16 + l16;
        float bv = bias[col];
#pragma unroll
        for (int mt = 0; mt < 4; ++mt) {
#pragma unroll
            for (int r = 0; r < 4; ++r) {
                int row = row0 + wm * 64 + mt * 16 + quad * 4 + r;
                if (row < NN) {
                    float v = acc[mt][nt][r] + bv;
                    if (relu) v = fmaxf(v, 0.f);
                    C[(size_t)row * ldc + coloff + col] = f2b(v);
                }
            }
        }
    }
}

// ---------------- fused mean-pool + head (4 waves, unrolled scan) ----------------

__device__ inline int lower_bound_i(const int* a, int n, int v) {
    int lo = 0, hi = n;
    while (lo < hi) {
        int m = (lo + hi) >> 1;
        if (a[m] < v) lo = m + 1; else hi = m;
    }
    return lo;
}

__global__ __launch_bounds__(256) void pool_head_kernel(const u32* __restrict__ h3u,
                                                        const int* __restrict__ batch,
                                                        const float* __restrict__ W1,
                                                        const float* __restrict__ b1,
                                                        const float* __restrict__ W2,
                                                        const float* __restrict__ b2,
                                                        float* __restrict__ out) {
    __shared__ float ps[256];
    __shared__ float p[128];
    __shared__ float hid[40];
    int g = blockIdx.x, t = threadIdx.x;
    int c = t & 127, half = t >> 7;        // 2 row-groups x 128 channels
    int w = c >> 1, odd = c & 1;
    int lo = lower_bound_i(batch, NN, g);
    int hi = lower_bound_i(batch, NN, g + 1);
    float s = 0.f;
    int i = lo + half;
    for (; i + 6 < hi; i += 8) {           // 4 independent loads in flight
        u32 v0 = h3u[(size_t)i * 64 + w];
        u32 v1 = h3u[(size_t)(i + 2) * 64 + w];
        u32 v2 = h3u[(size_t)(i + 4) * 64 + w];
        u32 v3 = h3u[(size_t)(i + 6) * 64 + w];
        s += (b2f(v0, odd) + b2f(v1, odd)) + (b2f(v2, odd) + b2f(v3, odd));
    }
    for (; i < hi; i += 2) s += b2f(h3u[(size_t)i * 64 + w], odd);
    ps[t] = s;
    __syncthreads();
    if (half == 0) p[c] = (ps[c] + ps[c + 128]) / fmaxf((float)(hi - lo), 1.f);
    __syncthreads();
    if (t < 40) {
        float v = b1[t];
        for (int k = 0; k < 128; ++k) v += p[k] * W1[k * 40 + t];
        hid[t] = v;
    }
    __syncthreads();
    if (t < 10) {
        float v = b2[t];
        for (int j = 0; j < 40; ++j) v += hid[j] * W2[j * 10 + t];
        out[g * 10 + t] = v;
    }
}

// ---------------- launch ----------------

extern "C" void kernel_launch(void* const* d_in, const int* in_sizes, int n_in,
                              void* d_out, int out_size, void* d_ws, size_t ws_size,
                              hipStream_t stream) {
    const float* x   = (const float*)d_in[0];
    const int* ei    = (const int*)d_in[1];
    const int* batch = (const int*)d_in[2];
    const float* Wr1 = (const float*)d_in[3];
    const float* br1 = (const float*)d_in[4];
    const float* Wo1 = (const float*)d_in[5];
    const float* Wr2 = (const float*)d_in[6];
    const float* br2 = (const float*)d_in[7];
    const float* Wo2 = (const float*)d_in[8];
    const float* Wr3 = (const float*)d_in[9];
    const float* br3 = (const float*)d_in[10];
    const float* Wo3 = (const float*)d_in[11];
    const float* W1  = (const float*)d_in[12];
    const float* b1  = (const float*)d_in[13];
    const float* W2  = (const float*)d_in[14];
    const float* b2  = (const float*)d_in[15];
    float* out = (float*)d_out;

    char* ws = (char*)d_ws;
    size_t off = 0;
    auto alloc = [&](size_t bytes) {
        void* p = ws + off;
        off += (bytes + 255) & ~(size_t)255;
        return p;
    };
    int* ofs      = (int*)alloc((NN + 1) * sizeof(int));
    int* bcnt     = (int*)alloc(256 * sizeof(int));
    u16* srcl     = (u16*)alloc((size_t)EE * 2);
    u16* ax       = (u16*)alloc((size_t)NN * 256 * 2);   // cols 0-127 agg, 128-255 x_bf
    u16* ah1      = (u16*)alloc((size_t)NN * 256 * 2);
    u16* h2       = (u16*)alloc((size_t)NN * 256 * 2);
    u16* t3o3     = (u16*)alloc((size_t)NN * 256 * 2);   // cols 0-127 t3, 128-255 o3
    u16* h3       = (u16*)alloc((size_t)NN * 128 * 2);   // bf16
    u16* BT1      = (u16*)alloc(128 * 256 * 2);
    u16* BT2      = (u16*)alloc(256 * 256 * 2);
    u16* BT3      = (u16*)alloc(256 * 256 * 2);
    float* bias3  = (float*)alloc(256 * sizeof(float));
    // pairs (12.85 MB) overlays h2 (25.6 MB): pairs lifetime ends at bfill,
    // h2 first written at gemm2.
    u32* pairs = (u32*)h2;

    hipMemsetAsync(bcnt, 0, 256 * sizeof(int), stream);

    // CSR pass 1 + x->bf16 + weight prep (fused, independent block ranges)
    bscatter_prep_kernel<<<SCBLKS + XBLKS + 256, 256, 0, stream>>>(
        ei, bcnt, pairs, x, ax, Wr1, Wo1, Wr2, Wo2, Wr3, Wo3, br3,
        BT1, BT2, BT3, bias3);
    // CSR pass 2
    bfill_kernel<<<NB, 512, 0, stream>>>(pairs, bcnt, ofs, srcl);

    // conv1
    pull_bf_kernel<<<NN * 64 / 256, 256, 0, stream>>>((const u32*)ax + 64, ofs, srcl, (u32*)ax);
    gemm_bf_kernel<<<dim3(1, 391), 256, 0, stream>>>(ax, BT1, br1, ah1, 256, 128, 1);
    // conv2
    pull_bf_kernel<<<NN * 64 / 256, 256, 0, stream>>>((const u32*)ah1 + 64, ofs, srcl, (u32*)ah1);
    gemm_bf_kernel<<<dim3(2, 391), 256, 0, stream>>>(ah1, BT2, br2, h2, 256, 0, 1);
    // conv3: [t3|o3] = h2 @ [Wr3|Wo3] (+ [0|br3])
    gemm_bf_kernel<<<dim3(2, 391), 256, 0, stream>>>(h2, BT3, bias3, t3o3, 256, 0, 0);
    // h3 = agg(t3) + o3  (bf16)
    pull3_kernel<<<NN * 64 / 256, 256, 0, stream>>>((const u32*)t3o3, ofs, srcl, (u32*)h3);

    // fused mean pool + head
    pool_head_kernel<<<GG, 256, 0, stream>>>((const u32*)h3, batch, W1, b1, W2, b2, out);
}